// Round 1
// baseline (2990.383 us; speedup 1.0000x reference)
//
#include <hip/hip_runtime.h>
#include <math.h>

// ProtoViT forward, fp32 correctness-first baseline.
// B=16, D=384, DEPTH=6, H=6, HD=64, P=2000, NP=4, N=196, T=197.

#define NBATCH 16
#define DIM 384
#define NLAYER 6
#define NHEAD 6
#define HDIM 64
#define NPROTO 2000
#define NPARTS 4
#define NPATCH 196
#define NTOK 197
#define MROWS (NBATCH*NTOK)   // 3152

// ---------------------------------------------------------------- transpose patch_w (D,768) -> (768,D)
__global__ void k_transpose_w(const float* __restrict__ pw, float* __restrict__ wT) {
    int idx = blockIdx.x * 256 + threadIdx.x;    // < 768*384
    int k = idx / 384, d = idx % 384;
    wT[idx] = pw[d * 768 + k];
}

// ---------------------------------------------------------------- im2col: (B*196, 768)
__global__ void k_im2col(const float* __restrict__ x, float* __restrict__ Acol) {
    int idx = blockIdx.x * 256 + threadIdx.x;    // < 3136*768
    int k = idx % 768;
    int m = idx / 768;
    int b = m / 196, n = m % 196;
    int c = k >> 8, rem = k & 255, i = rem >> 4, j = rem & 15;
    int py = n / 14, px = n % 14;
    Acol[idx] = x[((b * 3 + c) * 224 + py * 16 + i) * 224 + px * 16 + j];
}

// ---------------------------------------------------------------- generic fp32 GEMM: C = A(MxK) @ B(KxN) + bias [+res] [gelu]
// 64x64 tile, BK=16, 256 threads, 4x4 per thread.
__global__ __launch_bounds__(256) void k_gemm(const float* __restrict__ A,
                                              const float* __restrict__ Bm,
                                              const float* __restrict__ bias,
                                              const float* __restrict__ res,
                                              float* __restrict__ C,
                                              int M, int N, int K, int dogelu) {
    __shared__ float As[16][64];
    __shared__ float Bs[16][64];
    int n0 = blockIdx.x * 64;
    int m0 = blockIdx.y * 64;
    int tid = threadIdx.x;
    int tc = tid & 15, tr = tid >> 4;
    int arow = tid >> 2;           // 0..63
    int ak   = (tid & 3) << 2;     // 0,4,8,12
    int brow = tid >> 4;           // 0..15
    int bcol = (tid & 15) << 2;    // 0..60

    float acc[4][4];
    #pragma unroll
    for (int i = 0; i < 4; ++i)
        #pragma unroll
        for (int j = 0; j < 4; ++j) acc[i][j] = 0.f;

    for (int kt = 0; kt < K; kt += 16) {
        int am = m0 + arow;
        float4 av = make_float4(0.f, 0.f, 0.f, 0.f);
        if (am < M) av = *(const float4*)(A + (size_t)am * K + kt + ak);
        float4 bv = *(const float4*)(Bm + (size_t)(kt + brow) * N + n0 + bcol);
        __syncthreads();   // previous tile's compute done
        As[ak + 0][arow] = av.x; As[ak + 1][arow] = av.y;
        As[ak + 2][arow] = av.z; As[ak + 3][arow] = av.w;
        *(float4*)&Bs[brow][bcol] = bv;
        __syncthreads();
        #pragma unroll
        for (int k = 0; k < 16; ++k) {
            float4 a4 = *(const float4*)&As[k][tr << 2];
            float4 b4 = *(const float4*)&Bs[k][tc << 2];
            float aa[4] = {a4.x, a4.y, a4.z, a4.w};
            float bb[4] = {b4.x, b4.y, b4.z, b4.w};
            #pragma unroll
            for (int i = 0; i < 4; ++i)
                #pragma unroll
                for (int j = 0; j < 4; ++j) acc[i][j] += aa[i] * bb[j];
        }
    }
    int cn = n0 + (tc << 2);
    #pragma unroll
    for (int i = 0; i < 4; ++i) {
        int m = m0 + (tr << 2) + i;
        if (m >= M) continue;
        float o[4];
        #pragma unroll
        for (int j = 0; j < 4; ++j) {
            float v = acc[i][j] + bias[cn + j];
            if (res) v += res[(size_t)m * N + cn + j];
            if (dogelu) v = 0.5f * v * (1.0f + erff(v * 0.70710678118f));
            o[j] = v;
        }
        *(float4*)(C + (size_t)m * N + cn) = *(float4*)o;
    }
}

// ---------------------------------------------------------------- assemble tokens: cls + patches + pos
__global__ void k_assemble(const float* __restrict__ ptmp, const float* __restrict__ cls_tok,
                           const float* __restrict__ pos, float* __restrict__ tok) {
    int idx = blockIdx.x * 256 + threadIdx.x;   // < 16*197*384
    int d = idx % 384;
    int t = (idx / 384) % 197;
    int b = idx / (384 * 197);
    float v = (t == 0) ? cls_tok[d] : ptmp[((size_t)b * 196 + t - 1) * 384 + d];
    tok[idx] = v + pos[t * 384 + d];
}

// ---------------------------------------------------------------- layernorm: 1 wave per row (D=384)
__global__ __launch_bounds__(256) void k_ln(const float* __restrict__ X, const float* __restrict__ s,
                                            const float* __restrict__ bb, float* __restrict__ Y, int rows) {
    int wid = threadIdx.x >> 6, lane = threadIdx.x & 63;
    int row = blockIdx.x * 4 + wid;
    if (row >= rows) return;
    const float* x = X + (size_t)row * 384;
    float v[6], sum = 0.f, sq = 0.f;
    #pragma unroll
    for (int i = 0; i < 6; ++i) { float t = x[lane + 64 * i]; v[i] = t; sum += t; sq += t * t; }
    #pragma unroll
    for (int m = 32; m > 0; m >>= 1) { sum += __shfl_xor(sum, m); sq += __shfl_xor(sq, m); }
    float mean = sum * (1.f / 384.f);
    float var  = sq * (1.f / 384.f) - mean * mean;
    float rstd = rsqrtf(var + 1e-6f);
    float* y = Y + (size_t)row * 384;
    #pragma unroll
    for (int i = 0; i < 6; ++i) {
        int d = lane + 64 * i;
        y[d] = (v[i] - mean) * rstd * s[d] + bb[d];
    }
}

// ---------------------------------------------------------------- attention for one (b,h,row-chunk)
__global__ __launch_bounds__(256) void k_attn(const float* __restrict__ qkv, float* __restrict__ o) {
    __shared__ float ks[197 * 65];      // padded stride 65: conflict-free
    __shared__ float pbuf[4][204];
    int bh = blockIdx.x;
    int b = bh / 6, hh = bh % 6;
    const float* base = qkv + (size_t)b * 197 * 1152 + hh * 64;
    int tid = threadIdx.x;
    for (int idx = tid; idx < 197 * 64; idx += 256) {
        int j = idx >> 6, d = idx & 63;
        ks[j * 65 + d] = base[(size_t)j * 1152 + 384 + d];
    }
    __syncthreads();
    int wid = tid >> 6, lane = tid & 63;
    int r0 = blockIdx.y * 25;
    int r1 = min(197, r0 + 25);
    int j3 = (lane < 5) ? (192 + lane) : 0;   // clamp to avoid OOB LDS read; masked later
    for (int i = r0 + wid; i < r1; i += 4) {
        const float* q = base + (size_t)i * 1152;
        float s0 = 0.f, s1 = 0.f, s2 = 0.f, s3 = 0.f;
        for (int d = 0; d < 64; ++d) {
            float qd = q[d];
            s0 += qd * ks[lane * 65 + d];
            s1 += qd * ks[(lane + 64) * 65 + d];
            s2 += qd * ks[(lane + 128) * 65 + d];
            s3 += qd * ks[j3 * 65 + d];
        }
        s0 *= 0.125f; s1 *= 0.125f; s2 *= 0.125f;
        s3 = (lane < 5) ? s3 * 0.125f : -1e30f;
        float mx = fmaxf(fmaxf(s0, s1), fmaxf(s2, s3));
        #pragma unroll
        for (int m = 32; m > 0; m >>= 1) mx = fmaxf(mx, __shfl_xor(mx, m));
        float e0 = expf(s0 - mx), e1 = expf(s1 - mx), e2 = expf(s2 - mx), e3 = expf(s3 - mx);
        float sm = e0 + e1 + e2 + e3;
        #pragma unroll
        for (int m = 32; m > 0; m >>= 1) sm += __shfl_xor(sm, m);
        float inv = 1.f / sm;
        pbuf[wid][lane]        = e0 * inv;
        pbuf[wid][lane + 64]   = e1 * inv;
        pbuf[wid][lane + 128]  = e2 * inv;
        if (lane < 5) pbuf[wid][192 + lane] = e3 * inv;
        asm volatile("s_waitcnt lgkmcnt(0)" ::: "memory");  // wave-internal LDS visibility
        float acc = 0.f;
        const float* vb = base + 768 + lane;
        for (int j = 0; j < 197; ++j) acc += pbuf[wid][j] * vb[(size_t)j * 1152];
        o[((size_t)b * 197 + i) * 384 + hh * 64 + lane] = acc;
    }
}

// ---------------------------------------------------------------- cls output
__global__ void k_clsout(const float* __restrict__ tokn, float* __restrict__ out) {
    int idx = blockIdx.x * 256 + threadIdx.x;   // < 6144
    int b = idx / 384, d = idx % 384;
    out[idx] = tokn[(size_t)b * 197 * 384 + d];
}

// ---------------------------------------------------------------- feature columns normalized: fn (B,196,384)
__global__ __launch_bounds__(256) void k_fn(const float* __restrict__ tokn, float* __restrict__ fn) {
    int wid = threadIdx.x >> 6, lane = threadIdx.x & 63;
    int row = blockIdx.x * 4 + wid;   // < 3136
    int b = row / 196, n = row % 196;
    const float* xr = tokn + ((size_t)b * 197 + 1 + n) * 384;
    const float* cr = tokn + (size_t)b * 197 * 384;
    float v[6], ss = 0.f;
    #pragma unroll
    for (int i = 0; i < 6; ++i) {
        int d = lane + 64 * i;
        float t = xr[d] - cr[d];
        v[i] = t; ss += t * t;
    }
    #pragma unroll
    for (int m = 32; m > 0; m >>= 1) ss += __shfl_xor(ss, m);
    float inv = 1.f / fmaxf(sqrtf(ss), 1e-12f);
    #pragma unroll
    for (int i = 0; i < 6; ++i) fn[(size_t)row * 384 + lane + 64 * i] = v[i] * inv;
}

// ---------------------------------------------------------------- proto normalized + transposed: pn (P*4, 384)
__global__ __launch_bounds__(256) void k_pn(const float* __restrict__ proto, float* __restrict__ pn) {
    int p = blockIdx.x;
    int k = threadIdx.x >> 6, lane = threadIdx.x & 63;
    float v[6], ss = 0.f;
    #pragma unroll
    for (int i = 0; i < 6; ++i) {
        int d = lane + 64 * i;
        float t = proto[((size_t)p * 384 + d) * 4 + k];
        v[i] = t; ss += t * t;
    }
    #pragma unroll
    for (int m = 32; m > 0; m >>= 1) ss += __shfl_xor(ss, m);
    float inv = 1.f / fmaxf(sqrtf(ss), 1e-12f);
    #pragma unroll
    for (int i = 0; i < 6; ++i) pn[((size_t)p * 4 + k) * 384 + lane + 64 * i] = v[i] * inv;
}

// ---------------------------------------------------------------- dist GEMM + top-4 + score. block: (b, 16 protos)
__device__ inline void top4_insert(float v, float& t0, float& t1, float& t2, float& t3) {
    if (v > t3) {
        t3 = v;
        if (t3 > t2) { float t = t2; t2 = t3; t3 = t; }
        if (t2 > t1) { float t = t1; t1 = t2; t2 = t; }
        if (t1 > t0) { float t = t0; t0 = t1; t1 = t; }
    }
}

__global__ __launch_bounds__(256) void k_dist(const float* __restrict__ fn, const float* __restrict__ pn,
                                              const float* __restrict__ psel, float* __restrict__ out) {
    __shared__ float fs[64][68];      // [k][n], padded
    __shared__ float qs[64][68];      // [k][col], padded
    __shared__ float cand[16][65];
    int b = blockIdx.y;
    int p0 = blockIdx.x * 16;         // protos p0..p0+15
    int tid = threadIdx.x;
    int tn = tid >> 4;                // 0..15 -> rows tn*4..
    int tc = tid & 15;                // proto tc -> cols tc*4..tc*4+3
    float t0 = -1e30f, t1 = -1e30f, t2 = -1e30f, t3 = -1e30f;

    for (int nc = 0; nc < 4; ++nc) {
        int nb = nc * 64;
        float acc[4][4];
        #pragma unroll
        for (int i = 0; i < 4; ++i)
            #pragma unroll
            for (int j = 0; j < 4; ++j) acc[i][j] = 0.f;

        for (int kt = 0; kt < 384; kt += 64) {
            __syncthreads();
            #pragma unroll
            for (int q = 0; q < 4; ++q) {
                int r  = (tid >> 4) + q * 16;     // 0..63
                int c4 = (tid & 15) << 2;
                int n = nb + r;
                float4 v = make_float4(0.f, 0.f, 0.f, 0.f);
                if (n < 196) v = *(const float4*)(fn + ((size_t)b * 196 + n) * 384 + kt + c4);
                fs[c4 + 0][r] = v.x; fs[c4 + 1][r] = v.y; fs[c4 + 2][r] = v.z; fs[c4 + 3][r] = v.w;
                float4 w = *(const float4*)(pn + ((size_t)(p0 * 4) + r) * 384 + kt + c4);
                qs[c4 + 0][r] = w.x; qs[c4 + 1][r] = w.y; qs[c4 + 2][r] = w.z; qs[c4 + 3][r] = w.w;
            }
            __syncthreads();
            #pragma unroll 8
            for (int k = 0; k < 64; ++k) {
                float4 a4 = *(const float4*)&fs[k][tn << 2];
                float4 b4 = *(const float4*)&qs[k][tc << 2];
                float aa[4] = {a4.x, a4.y, a4.z, a4.w};
                float bb[4] = {b4.x, b4.y, b4.z, b4.w};
                #pragma unroll
                for (int i = 0; i < 4; ++i)
                    #pragma unroll
                    for (int j = 0; j < 4; ++j) acc[i][j] += aa[i] * bb[j];
            }
        }
        #pragma unroll
        for (int i = 0; i < 4; ++i) {
            int n = nb + (tn << 2) + i;
            #pragma unroll
            for (int j = 0; j < 4; ++j) {
                float v = (n < 196) ? acc[i][j] : -1e30f;
                top4_insert(v, t0, t1, t2, t3);
            }
        }
    }
    // merge per proto: 16 threads (tn) x 4 candidates each
    cand[tc][(tn << 2) + 0] = t0;
    cand[tc][(tn << 2) + 1] = t1;
    cand[tc][(tn << 2) + 2] = t2;
    cand[tc][(tn << 2) + 3] = t3;
    __syncthreads();
    if (tid < 16) {
        int p = tid;
        float best[4];
        for (int pass = 0; pass < 4; ++pass) {
            float m = -1e30f; int mi = 0;
            for (int i = 0; i < 64; ++i) {
                float v = cand[p][i];
                if (v > m) { m = v; mi = i; }
            }
            cand[p][mi] = -1e30f;
            best[pass] = m;
        }
        int pg = p0 + p;
        float sl[4]; float fac = 1e-10f;
        #pragma unroll
        for (int i = 0; i < 4; ++i) {
            sl[i] = 1.f / (1.f + expf(-psel[pg * 4 + i] * 100.f));
            fac += sl[i];
        }
        float score = 0.f;
        #pragma unroll
        for (int i = 0; i < 4; ++i) score += best[i] * (sl[i] * 4.f / fac);
        out[6144 + (size_t)b * 2000 + pg] = score;
    }
}

// ---------------------------------------------------------------- host launcher
extern "C" void kernel_launch(void* const* d_in, const int* in_sizes, int n_in,
                              void* d_out, int out_size, void* d_ws, size_t ws_size,
                              hipStream_t stream) {
    const float* x       = (const float*)d_in[0];
    const float* patch_w = (const float*)d_in[1];
    const float* patch_b = (const float*)d_in[2];
    const float* cls_tok = (const float*)d_in[3];
    const float* pos     = (const float*)d_in[4];
    const float* ln1_s   = (const float*)d_in[5];
    const float* ln1_b   = (const float*)d_in[6];
    const float* qkv_w   = (const float*)d_in[7];
    const float* qkv_b   = (const float*)d_in[8];
    const float* proj_w  = (const float*)d_in[9];
    const float* proj_b  = (const float*)d_in[10];
    const float* ln2_s   = (const float*)d_in[11];
    const float* ln2_b   = (const float*)d_in[12];
    const float* fc1_w   = (const float*)d_in[13];
    const float* fc1_b   = (const float*)d_in[14];
    const float* fc2_w   = (const float*)d_in[15];
    const float* fc2_b   = (const float*)d_in[16];
    const float* norm_s  = (const float*)d_in[17];
    const float* norm_b  = (const float*)d_in[18];
    const float* proto   = (const float*)d_in[19];
    const float* psel    = (const float*)d_in[20];
    float* out = (float*)d_out;
    float* ws  = (float*)d_ws;

    // workspace layout (floats), total ~20.3M floats = 81.2 MB
    float* wT   = ws;                  // 294912
    float* Acol = wT   + 294912;       // 2408448
    float* ptmp = Acol + 2408448;      // 1204224
    float* tok  = ptmp + 1204224;      // 1210368
    float* h    = tok  + 1210368;      // 1210368
    float* qkvb = h    + 1210368;      // 3631104
    float* ao   = qkvb + 3631104;      // 1210368
    float* hbig = ao   + 1210368;      // 4841472
    float* fnb  = hbig + 4841472;      // 1204224
    float* pnb  = fnb  + 1204224;      // 3072000

    k_transpose_w<<<1152, 256, 0, stream>>>(patch_w, wT);
    k_im2col<<<9408, 256, 0, stream>>>(x, Acol);
    k_gemm<<<dim3(6, 49), 256, 0, stream>>>(Acol, wT, patch_b, nullptr, ptmp, 3136, 384, 768, 0);
    k_assemble<<<4728, 256, 0, stream>>>(ptmp, cls_tok, pos, tok);

    for (int l = 0; l < NLAYER; ++l) {
        k_ln<<<788, 256, 0, stream>>>(tok, ln1_s + l * 384, ln1_b + l * 384, h, MROWS);
        k_gemm<<<dim3(18, 50), 256, 0, stream>>>(h, qkv_w + (size_t)l * 384 * 1152, qkv_b + l * 1152,
                                                 nullptr, qkvb, MROWS, 1152, 384, 0);
        k_attn<<<dim3(96, 8), 256, 0, stream>>>(qkvb, ao);
        k_gemm<<<dim3(6, 50), 256, 0, stream>>>(ao, proj_w + (size_t)l * 384 * 384, proj_b + l * 384,
                                                tok, tok, MROWS, 384, 384, 0);
        k_ln<<<788, 256, 0, stream>>>(tok, ln2_s + l * 384, ln2_b + l * 384, h, MROWS);
        k_gemm<<<dim3(24, 50), 256, 0, stream>>>(h, fc1_w + (size_t)l * 384 * 1536, fc1_b + l * 1536,
                                                 nullptr, hbig, MROWS, 1536, 384, 1);
        k_gemm<<<dim3(6, 50), 256, 0, stream>>>(hbig, fc2_w + (size_t)l * 1536 * 384, fc2_b + l * 384,
                                                tok, tok, MROWS, 384, 1536, 0);
    }

    k_ln<<<788, 256, 0, stream>>>(tok, norm_s, norm_b, h, MROWS);
    k_clsout<<<24, 256, 0, stream>>>(h, out);
    k_fn<<<784, 256, 0, stream>>>(h, fnb);
    k_pn<<<2000, 256, 0, stream>>>(proto, pnb);
    k_dist<<<dim3(125, 16), 256, 0, stream>>>(fnb, pnb, psel, out);
}

// Round 2
// 1955.121 us; speedup vs baseline: 1.5295x; 1.5295x over previous
//
#include <hip/hip_runtime.h>
#include <hip/hip_bf16.h>
#include <math.h>

// ProtoViT forward: bf16-MFMA GEMMs + fp32 residual/LN/softmax path.
// B=16, D=384, DEPTH=6, H=6, HD=64, P=2000, NP=4, N=196, T=197.

#define MROWS 3152   // 16*197

typedef short bf16x8 __attribute__((ext_vector_type(8)));
typedef float f32x4 __attribute__((ext_vector_type(4)));
typedef unsigned short u16;

__device__ __forceinline__ void async_copy16(void* lds, const void* g) {
    __builtin_amdgcn_global_load_lds((const __attribute__((address_space(1))) unsigned int*)g,
                                     (__attribute__((address_space(3))) unsigned int*)lds,
                                     16, 0, 0);
}

// ---------------------------------------------------------------- fp32 -> bf16 elementwise
__global__ void k_cvt(const float* __restrict__ in, __hip_bfloat16* __restrict__ o, int n) {
    int i = blockIdx.x * 256 + threadIdx.x;
    if (i < n) o[i] = __float2bfloat16(in[i]);
}

// ---------------------------------------------------------------- weight transpose (K,N) f32 -> (N,K) bf16, per layer z
__global__ __launch_bounds__(256) void k_wt(const float* __restrict__ W, __hip_bfloat16* __restrict__ Wt,
                                            int K, int N) {
    __shared__ float t[32][33];
    const float* src = W + (size_t)blockIdx.z * K * N;
    __hip_bfloat16* dst = Wt + (size_t)blockIdx.z * K * N;
    int n0 = blockIdx.x * 32, k0 = blockIdx.y * 32;
    int tx = threadIdx.x & 31, ty = threadIdx.x >> 5;   // 32 x 8
    #pragma unroll
    for (int i = 0; i < 4; ++i) t[ty + i * 8][tx] = src[(size_t)(k0 + ty + i * 8) * N + n0 + tx];
    __syncthreads();
    #pragma unroll
    for (int i = 0; i < 4; ++i)
        dst[(size_t)(n0 + ty + i * 8) * K + k0 + tx] = __float2bfloat16(t[tx][ty + i * 8]);
}

// ---------------------------------------------------------------- im2col -> bf16 (B*196, 768)
__global__ void k_im2col(const float* __restrict__ x, __hip_bfloat16* __restrict__ Acol) {
    int idx = blockIdx.x * 256 + threadIdx.x;    // < 3136*768
    int k = idx % 768;
    int m = idx / 768;
    int b = m / 196, n = m % 196;
    int c = k >> 8, rem = k & 255, i = rem >> 4, j = rem & 15;
    int py = n / 14, px = n % 14;
    Acol[idx] = __float2bfloat16(x[((b * 3 + c) * 224 + py * 16 + i) * 224 + px * 16 + j]);
}

// ---------------------------------------------------------------- bf16 MFMA GEMM
// C(M,N) = A(M,K)bf16 @ Bt(N,K)bf16^T + bias, optional +res(fp32), optional gelu,
// output fp32 (Cf) or bf16 (Cb). 128x128 tile, BK=64, 4 waves, global_load_lds.
template<int RES, int GELU, int BF16OUT>
__global__ __launch_bounds__(256) void k_mfma_gemm(
    const u16* __restrict__ A, const u16* __restrict__ Bt,
    const float* __restrict__ bias, const float* __restrict__ res,
    float* __restrict__ Cf, __hip_bfloat16* __restrict__ Cb,
    int M, int N, int K)
{
    __shared__ u16 As[128 * 64];
    __shared__ u16 Bs[128 * 64];
    const int tid = threadIdx.x;
    const int wid = tid >> 6, lane = tid & 63;
    const int m0 = blockIdx.y * 128, n0 = blockIdx.x * 128;
    const int srow = tid >> 3;          // 0..31 within staging group
    const int selem = (tid & 7) << 3;   // element offset 0..56 (16B chunks)
    const int wm = (wid >> 1) * 64, wn = (wid & 1) * 64;

    f32x4 acc[4][4] = {};

    for (int kt = 0; kt < K; kt += 64) {
        __syncthreads();
        #pragma unroll
        for (int g = 0; g < 4; ++g) {
            int r = g * 32 + srow;
            int gr = m0 + r; if (gr > M - 1) gr = M - 1;
            async_copy16(&As[r * 64 + selem], A + (size_t)gr * K + kt + selem);
            async_copy16(&Bs[r * 64 + selem], Bt + (size_t)(n0 + r) * K + kt + selem);
        }
        __syncthreads();
        #pragma unroll
        for (int ks = 0; ks < 64; ks += 32) {
            const int kk = ks + ((lane >> 4) << 3);
            bf16x8 af[4], bfr[4];
            #pragma unroll
            for (int i = 0; i < 4; ++i)
                af[i] = *(const bf16x8*)&As[(wm + i * 16 + (lane & 15)) * 64 + kk];
            #pragma unroll
            for (int j = 0; j < 4; ++j)
                bfr[j] = *(const bf16x8*)&Bs[(wn + j * 16 + (lane & 15)) * 64 + kk];
            #pragma unroll
            for (int i = 0; i < 4; ++i)
                #pragma unroll
                for (int j = 0; j < 4; ++j)
                    acc[i][j] = __builtin_amdgcn_mfma_f32_16x16x32_bf16(af[i], bfr[j], acc[i][j], 0, 0, 0);
        }
    }
    const int cl = lane & 15, rg = (lane >> 4) << 2;
    #pragma unroll
    for (int i = 0; i < 4; ++i) {
        #pragma unroll
        for (int j = 0; j < 4; ++j) {
            const int col = n0 + wn + j * 16 + cl;
            const float bv = bias[col];
            #pragma unroll
            for (int r = 0; r < 4; ++r) {
                const int row = m0 + wm + i * 16 + rg + r;
                if (row >= M) continue;
                float v = acc[i][j][r] + bv;
                if (RES) v += res[(size_t)row * N + col];
                if (GELU) v = 0.5f * v * (1.0f + erff(v * 0.70710678118f));
                if (BF16OUT) Cb[(size_t)row * N + col] = __float2bfloat16(v);
                else         Cf[(size_t)row * N + col] = v;
            }
        }
    }
}

// ---------------------------------------------------------------- assemble tokens: cls + patches + pos (fp32)
__global__ void k_assemble(const float* __restrict__ ptmp, const float* __restrict__ cls_tok,
                           const float* __restrict__ pos, float* __restrict__ tok) {
    int idx = blockIdx.x * 256 + threadIdx.x;   // < 16*197*384
    int d = idx % 384;
    int t = (idx / 384) % 197;
    int b = idx / (384 * 197);
    float v = (t == 0) ? cls_tok[d] : ptmp[((size_t)b * 196 + t - 1) * 384 + d];
    tok[idx] = v + pos[t * 384 + d];
}

// ---------------------------------------------------------------- layernorm (fp32 compute), OT output
template<typename OT>
__global__ __launch_bounds__(256) void k_ln(const float* __restrict__ X, const float* __restrict__ s,
                                            const float* __restrict__ bb, OT* __restrict__ Y, int rows) {
    int wid = threadIdx.x >> 6, lane = threadIdx.x & 63;
    int row = blockIdx.x * 4 + wid;
    if (row >= rows) return;
    const float* x = X + (size_t)row * 384;
    float v[6], sum = 0.f, sq = 0.f;
    #pragma unroll
    for (int i = 0; i < 6; ++i) { float t = x[lane + 64 * i]; v[i] = t; sum += t; sq += t * t; }
    #pragma unroll
    for (int m = 32; m > 0; m >>= 1) { sum += __shfl_xor(sum, m); sq += __shfl_xor(sq, m); }
    float mean = sum * (1.f / 384.f);
    float var  = sq * (1.f / 384.f) - mean * mean;
    float rstd = rsqrtf(var + 1e-6f);
    OT* y = Y + (size_t)row * 384;
    #pragma unroll
    for (int i = 0; i < 6; ++i) {
        int d = lane + 64 * i;
        float o = (v[i] - mean) * rstd * s[d] + bb[d];
        y[d] = (OT)o;
    }
}

// ---------------------------------------------------------------- attention (fp32), bf16 out
__global__ __launch_bounds__(256) void k_attn(const float* __restrict__ qkv, __hip_bfloat16* __restrict__ o) {
    __shared__ float ks[197 * 65];
    __shared__ float pbuf[4][204];
    int bh = blockIdx.x;
    int b = bh / 6, hh = bh % 6;
    const float* base = qkv + (size_t)b * 197 * 1152 + hh * 64;
    int tid = threadIdx.x;
    for (int idx = tid; idx < 197 * 64; idx += 256) {
        int j = idx >> 6, d = idx & 63;
        ks[j * 65 + d] = base[(size_t)j * 1152 + 384 + d];
    }
    __syncthreads();
    int wid = tid >> 6, lane = tid & 63;
    int r0 = blockIdx.y * 25;
    int r1 = min(197, r0 + 25);
    int j3 = (lane < 5) ? (192 + lane) : 0;
    for (int i = r0 + wid; i < r1; i += 4) {
        const float* q = base + (size_t)i * 1152;
        float s0 = 0.f, s1 = 0.f, s2 = 0.f, s3 = 0.f;
        for (int d = 0; d < 64; ++d) {
            float qd = q[d];
            s0 += qd * ks[lane * 65 + d];
            s1 += qd * ks[(lane + 64) * 65 + d];
            s2 += qd * ks[(lane + 128) * 65 + d];
            s3 += qd * ks[j3 * 65 + d];
        }
        s0 *= 0.125f; s1 *= 0.125f; s2 *= 0.125f;
        s3 = (lane < 5) ? s3 * 0.125f : -1e30f;
        float mx = fmaxf(fmaxf(s0, s1), fmaxf(s2, s3));
        #pragma unroll
        for (int m = 32; m > 0; m >>= 1) mx = fmaxf(mx, __shfl_xor(mx, m));
        float e0 = expf(s0 - mx), e1 = expf(s1 - mx), e2 = expf(s2 - mx), e3 = expf(s3 - mx);
        float sm = e0 + e1 + e2 + e3;
        #pragma unroll
        for (int m = 32; m > 0; m >>= 1) sm += __shfl_xor(sm, m);
        float inv = 1.f / sm;
        pbuf[wid][lane]        = e0 * inv;
        pbuf[wid][lane + 64]   = e1 * inv;
        pbuf[wid][lane + 128]  = e2 * inv;
        if (lane < 5) pbuf[wid][192 + lane] = e3 * inv;
        asm volatile("s_waitcnt lgkmcnt(0)" ::: "memory");
        float acc = 0.f;
        const float* vb = base + 768 + lane;
        for (int j = 0; j < 197; ++j) acc += pbuf[wid][j] * vb[(size_t)j * 1152];
        o[((size_t)b * 197 + i) * 384 + hh * 64 + lane] = __float2bfloat16(acc);
    }
}

// ---------------------------------------------------------------- cls output (fp32)
__global__ void k_clsout(const float* __restrict__ tokn, float* __restrict__ out) {
    int idx = blockIdx.x * 256 + threadIdx.x;   // < 6144
    int b = idx / 384, d = idx % 384;
    out[idx] = tokn[(size_t)b * 197 * 384 + d];
}

// ---------------------------------------------------------------- feature normalize -> bf16 (B*196, 384)
__global__ __launch_bounds__(256) void k_fn(const float* __restrict__ tokn, __hip_bfloat16* __restrict__ fn) {
    int wid = threadIdx.x >> 6, lane = threadIdx.x & 63;
    int row = blockIdx.x * 4 + wid;   // < 3136
    int b = row / 196, n = row % 196;
    const float* xr = tokn + ((size_t)b * 197 + 1 + n) * 384;
    const float* cr = tokn + (size_t)b * 197 * 384;
    float v[6], ss = 0.f;
    #pragma unroll
    for (int i = 0; i < 6; ++i) {
        int d = lane + 64 * i;
        float t = xr[d] - cr[d];
        v[i] = t; ss += t * t;
    }
    #pragma unroll
    for (int m = 32; m > 0; m >>= 1) ss += __shfl_xor(ss, m);
    float inv = 1.f / fmaxf(sqrtf(ss), 1e-12f);
    #pragma unroll
    for (int i = 0; i < 6; ++i) fn[(size_t)row * 384 + lane + 64 * i] = __float2bfloat16(v[i] * inv);
}

// ---------------------------------------------------------------- proto normalize + transpose -> bf16 (8000, 384)
__global__ __launch_bounds__(256) void k_pn(const float* __restrict__ proto, __hip_bfloat16* __restrict__ pn) {
    int p = blockIdx.x;
    int k = threadIdx.x >> 6, lane = threadIdx.x & 63;
    float v[6], ss = 0.f;
    #pragma unroll
    for (int i = 0; i < 6; ++i) {
        int d = lane + 64 * i;
        float t = proto[((size_t)p * 384 + d) * 4 + k];
        v[i] = t; ss += t * t;
    }
    #pragma unroll
    for (int m = 32; m > 0; m >>= 1) ss += __shfl_xor(ss, m);
    float inv = 1.f / fmaxf(sqrtf(ss), 1e-12f);
    #pragma unroll
    for (int i = 0; i < 6; ++i) pn[((size_t)p * 4 + k) * 384 + lane + 64 * i] = __float2bfloat16(v[i] * inv);
}

// ---------------------------------------------------------------- top4 helper
__device__ __forceinline__ void top4_insert(float v, float& t0, float& t1, float& t2, float& t3) {
    if (v > t3) {
        t3 = v;
        if (t3 > t2) { float t = t2; t2 = t3; t3 = t; }
        if (t2 > t1) { float t = t1; t1 = t2; t2 = t; }
        if (t1 > t0) { float t = t0; t0 = t1; t1 = t; }
    }
}

// ---------------------------------------------------------------- dist: bf16 MFMA GEMM + fused top-4 + score
// block = (b, 32 protos=128 rows). N padded 196->208 (13 frags). K=384.
__global__ __launch_bounds__(256) void k_dist_mfma(
    const __hip_bfloat16* __restrict__ fnb, const __hip_bfloat16* __restrict__ pnb,
    const float* __restrict__ psel, float* __restrict__ out)
{
    __shared__ u16 Ap[128 * 64];   // proto tile, XOR-swizzled rows (128B)
    __shared__ u16 Bf[208 * 64];   // patch tile, XOR-swizzled
    const u16* fn = (const u16*)fnb;
    const u16* pn = (const u16*)pnb;
    const int b = blockIdx.x;
    const int pb = blockIdx.y;          // proto-row block: rows pb*128
    const int tid = threadIdx.x, wid = tid >> 6, lane = tid & 63;
    const int srow = tid >> 3;          // 0..31
    const int selem = (tid & 7) << 3;   // 0..56

    f32x4 acc[2][13] = {};

    for (int kt = 0; kt < 384; kt += 64) {
        uint4 ar[4], br[7];
        #pragma unroll
        for (int g = 0; g < 4; ++g) {
            int r = g * 32 + srow;
            int gr = pb * 128 + r; if (gr > 7999) gr = 7999;
            ar[g] = *(const uint4*)(pn + (size_t)gr * 384 + kt + selem);
        }
        #pragma unroll
        for (int g = 0; g < 7; ++g) {
            int r = g * 32 + srow;
            int fr = r > 195 ? 195 : r;
            br[g] = *(const uint4*)(fn + ((size_t)b * 196 + fr) * 384 + kt + selem);
        }
        __syncthreads();
        #pragma unroll
        for (int g = 0; g < 4; ++g) {
            int r = g * 32 + srow;
            *(uint4*)&Ap[r * 64 + (selem ^ ((r & 7) << 3))] = ar[g];
        }
        #pragma unroll
        for (int g = 0; g < 7; ++g) {
            int r = g * 32 + srow;
            if (r < 208) *(uint4*)&Bf[r * 64 + (selem ^ ((r & 7) << 3))] = br[g];
        }
        __syncthreads();
        #pragma unroll
        for (int ks = 0; ks < 64; ks += 32) {
            const int kk = ks + ((lane >> 4) << 3);
            bf16x8 af[2];
            #pragma unroll
            for (int i = 0; i < 2; ++i) {
                int r = wid * 32 + i * 16 + (lane & 15);
                af[i] = *(const bf16x8*)&Ap[r * 64 + (kk ^ ((r & 7) << 3))];
            }
            #pragma unroll
            for (int j = 0; j < 13; ++j) {
                int r = j * 16 + (lane & 15);
                bf16x8 bj = *(const bf16x8*)&Bf[r * 64 + (kk ^ ((r & 7) << 3))];
                acc[0][j] = __builtin_amdgcn_mfma_f32_16x16x32_bf16(af[0], bj, acc[0][j], 0, 0, 0);
                acc[1][j] = __builtin_amdgcn_mfma_f32_16x16x32_bf16(af[1], bj, acc[1][j], 0, 0, 0);
            }
        }
    }
    // top-4 per proto (4 rows = 4 k-slots held in regs r0..r3 of one lane group)
    const int cl = lane & 15;
    #pragma unroll
    for (int mi = 0; mi < 2; ++mi) {
        float t0 = -1e30f, t1 = -1e30f, t2 = -1e30f, t3 = -1e30f;
        #pragma unroll
        for (int j = 0; j < 13; ++j) {
            if (j * 16 + cl >= 196) continue;
            #pragma unroll
            for (int r = 0; r < 4; ++r) top4_insert(acc[mi][j][r], t0, t1, t2, t3);
        }
        #pragma unroll
        for (int m = 1; m <= 8; m <<= 1) {
            float u0 = __shfl_xor(t0, m), u1 = __shfl_xor(t1, m);
            float u2 = __shfl_xor(t2, m), u3 = __shfl_xor(t3, m);
            top4_insert(u0, t0, t1, t2, t3);
            top4_insert(u1, t0, t1, t2, t3);
            top4_insert(u2, t0, t1, t2, t3);
            top4_insert(u3, t0, t1, t2, t3);
        }
        if (cl == 0) {
            int proto = pb * 32 + wid * 8 + mi * 4 + (lane >> 4);
            if (proto < 2000) {
                float sl[4], fac = 1e-10f;
                #pragma unroll
                for (int i = 0; i < 4; ++i) {
                    sl[i] = 1.f / (1.f + expf(-psel[proto * 4 + i] * 100.f));
                    fac += sl[i];
                }
                float score = (t0 * sl[0] + t1 * sl[1] + t2 * sl[2] + t3 * sl[3]) * 4.f / fac;
                out[6144 + (size_t)b * 2000 + proto] = score;
            }
        }
    }
}

// ---------------------------------------------------------------- host launcher
extern "C" void kernel_launch(void* const* d_in, const int* in_sizes, int n_in,
                              void* d_out, int out_size, void* d_ws, size_t ws_size,
                              hipStream_t stream) {
    const float* x       = (const float*)d_in[0];
    const float* patch_w = (const float*)d_in[1];
    const float* patch_b = (const float*)d_in[2];
    const float* cls_tok = (const float*)d_in[3];
    const float* pos     = (const float*)d_in[4];
    const float* ln1_s   = (const float*)d_in[5];
    const float* ln1_b   = (const float*)d_in[6];
    const float* qkv_w   = (const float*)d_in[7];
    const float* qkv_b   = (const float*)d_in[8];
    const float* proj_w  = (const float*)d_in[9];
    const float* proj_b  = (const float*)d_in[10];
    const float* ln2_s   = (const float*)d_in[11];
    const float* ln2_b   = (const float*)d_in[12];
    const float* fc1_w   = (const float*)d_in[13];
    const float* fc1_b   = (const float*)d_in[14];
    const float* fc2_w   = (const float*)d_in[15];
    const float* fc2_b   = (const float*)d_in[16];
    const float* norm_s  = (const float*)d_in[17];
    const float* norm_b  = (const float*)d_in[18];
    const float* proto   = (const float*)d_in[19];
    const float* psel    = (const float*)d_in[20];
    float* out = (float*)d_out;
    char* w = (char*)d_ws;

    // byte offsets, 256-aligned
    __hip_bfloat16* wPb  = (__hip_bfloat16*)(w);             // 384*768*2      = 589824
    __hip_bfloat16* wQ   = (__hip_bfloat16*)(w + 589824);    // 6*1152*384*2   = 5308416
    __hip_bfloat16* wPr  = (__hip_bfloat16*)(w + 5898240);   // 6*384*384*2    = 1769472
    __hip_bfloat16* wF1  = (__hip_bfloat16*)(w + 7667712);   // 6*384*1536*2   = 7077888
    __hip_bfloat16* wF2  = (__hip_bfloat16*)(w + 14745600);  // 6*1536*384*2   = 7077888
    __hip_bfloat16* Acol = (__hip_bfloat16*)(w + 21823488);  // 3136*768*2     = 4816896
    float*          ptmp = (float*)         (w + 26640384);  // 3136*384*4     = 4816896
    float*          tok  = (float*)         (w + 31457280);  // 3152*384*4     = 4841472
    __hip_bfloat16* hbf  = (__hip_bfloat16*)(w + 36298752);  // 3152*384*2     = 2420736
    float*          qkvb = (float*)         (w + 38719488);  // 3152*1152*4    = 14524416
    __hip_bfloat16* aob  = (__hip_bfloat16*)(w + 53243904);  // 3152*384*2     = 2420736
    __hip_bfloat16* hbig = (__hip_bfloat16*)(w + 55664640);  // 3152*1536*2    = 9682944
    float*          hf   = (float*)         (w + 65347584);  // 3152*384*4     = 4841472
    __hip_bfloat16* fnb  = (__hip_bfloat16*)(w + 70189056);  // 3136*384*2     = 2408448
    __hip_bfloat16* pnb  = (__hip_bfloat16*)(w + 72597504);  // 8000*384*2     = 6144000
    // end: 78741504 bytes

    // weight prep
    k_cvt<<<1152, 256, 0, stream>>>(patch_w, wPb, 294912);
    k_wt<<<dim3(36, 12, 6), 256, 0, stream>>>(qkv_w, wQ, 384, 1152);
    k_wt<<<dim3(12, 12, 6), 256, 0, stream>>>(proj_w, wPr, 384, 384);
    k_wt<<<dim3(48, 12, 6), 256, 0, stream>>>(fc1_w, wF1, 384, 1536);
    k_wt<<<dim3(12, 48, 6), 256, 0, stream>>>(fc2_w, wF2, 1536, 384);

    // patch embed
    k_im2col<<<9408, 256, 0, stream>>>(x, Acol);
    k_mfma_gemm<0,0,0><<<dim3(3, 25), 256, 0, stream>>>(
        (const u16*)Acol, (const u16*)wPb, patch_b, nullptr, ptmp, nullptr, 3136, 384, 768);
    k_assemble<<<4728, 256, 0, stream>>>(ptmp, cls_tok, pos, tok);

    for (int l = 0; l < 6; ++l) {
        k_ln<__hip_bfloat16><<<788, 256, 0, stream>>>(tok, ln1_s + l * 384, ln1_b + l * 384, hbf, MROWS);
        k_mfma_gemm<0,0,0><<<dim3(9, 25), 256, 0, stream>>>(
            (const u16*)hbf, (const u16*)(wQ + (size_t)l * 1152 * 384), qkv_b + l * 1152,
            nullptr, qkvb, nullptr, MROWS, 1152, 384);
        k_attn<<<dim3(96, 8), 256, 0, stream>>>(qkvb, aob);
        k_mfma_gemm<1,0,0><<<dim3(3, 25), 256, 0, stream>>>(
            (const u16*)aob, (const u16*)(wPr + (size_t)l * 384 * 384), proj_b + l * 384,
            tok, tok, nullptr, MROWS, 384, 384);
        k_ln<__hip_bfloat16><<<788, 256, 0, stream>>>(tok, ln2_s + l * 384, ln2_b + l * 384, hbf, MROWS);
        k_mfma_gemm<0,1,1><<<dim3(12, 25), 256, 0, stream>>>(
            (const u16*)hbf, (const u16*)(wF1 + (size_t)l * 1536 * 384), fc1_b + l * 1536,
            nullptr, nullptr, hbig, MROWS, 1536, 384);
        k_mfma_gemm<1,0,0><<<dim3(3, 25), 256, 0, stream>>>(
            (const u16*)hbig, (const u16*)(wF2 + (size_t)l * 384 * 1536), fc2_b + l * 384,
            tok, tok, nullptr, MROWS, 384, 1536);
    }

    k_ln<float><<<788, 256, 0, stream>>>(tok, norm_s, norm_b, hf, MROWS);
    k_clsout<<<24, 256, 0, stream>>>(hf, out);
    k_fn<<<784, 256, 0, stream>>>(hf, fnb);
    k_pn<<<2000, 256, 0, stream>>>(proto, pnb);
    k_dist_mfma<<<dim3(16, 63), 256, 0, stream>>>(fnb, pnb, psel, out);
}

// Round 3
// 985.077 us; speedup vs baseline: 3.0357x; 1.9847x over previous
//
#include <hip/hip_runtime.h>
#include <hip/hip_bf16.h>
#include <math.h>

// ProtoViT forward: bf16-MFMA GEMMs + MFMA attention + fp32 residual/LN path.
// B=16, D=384, DEPTH=6, H=6, HD=64, P=2000, NP=4, N=196, T=197.

#define MROWS 3152   // 16*197

typedef short bf16x8 __attribute__((ext_vector_type(8)));
typedef float f32x4 __attribute__((ext_vector_type(4)));
typedef unsigned short u16;

__device__ __forceinline__ void async_copy16(void* lds, const void* g) {
    __builtin_amdgcn_global_load_lds((const __attribute__((address_space(1))) unsigned int*)g,
                                     (__attribute__((address_space(3))) unsigned int*)lds,
                                     16, 0, 0);
}

__device__ __forceinline__ u16 f2b(float x) {
    __hip_bfloat16 h = __float2bfloat16(x);
    return *(u16*)&h;
}

// ---------------------------------------------------------------- fp32 -> bf16 elementwise
__global__ void k_cvt(const float* __restrict__ in, __hip_bfloat16* __restrict__ o, int n) {
    int i = blockIdx.x * 256 + threadIdx.x;
    if (i < n) o[i] = __float2bfloat16(in[i]);
}

// ---------------------------------------------------------------- weight transpose (K,N) f32 -> (N,K) bf16, per layer z
__global__ __launch_bounds__(256) void k_wt(const float* __restrict__ W, __hip_bfloat16* __restrict__ Wt,
                                            int K, int N) {
    __shared__ float t[32][33];
    const float* src = W + (size_t)blockIdx.z * K * N;
    __hip_bfloat16* dst = Wt + (size_t)blockIdx.z * K * N;
    int n0 = blockIdx.x * 32, k0 = blockIdx.y * 32;
    int tx = threadIdx.x & 31, ty = threadIdx.x >> 5;   // 32 x 8
    #pragma unroll
    for (int i = 0; i < 4; ++i) t[ty + i * 8][tx] = src[(size_t)(k0 + ty + i * 8) * N + n0 + tx];
    __syncthreads();
    #pragma unroll
    for (int i = 0; i < 4; ++i)
        dst[(size_t)(n0 + ty + i * 8) * K + k0 + tx] = __float2bfloat16(t[tx][ty + i * 8]);
}

// ---------------------------------------------------------------- im2col -> bf16 (B*196, 768)
__global__ void k_im2col(const float* __restrict__ x, __hip_bfloat16* __restrict__ Acol) {
    int idx = blockIdx.x * 256 + threadIdx.x;    // < 3136*768
    int k = idx % 768;
    int m = idx / 768;
    int b = m / 196, n = m % 196;
    int c = k >> 8, rem = k & 255, i = rem >> 4, j = rem & 15;
    int py = n / 14, px = n % 14;
    Acol[idx] = __float2bfloat16(x[((b * 3 + c) * 224 + py * 16 + i) * 224 + px * 16 + j]);
}

// ---------------------------------------------------------------- bf16 MFMA GEMM
// C(M,N) = A(M,K)bf16 @ Bt(N,K)bf16^T + bias, optional +res(fp32), optional gelu,
// output fp32 (Cf) or bf16 (Cb). 128x128 tile, BK=64, 4 waves, global_load_lds.
template<int RES, int GELU, int BF16OUT>
__global__ __launch_bounds__(256) void k_mfma_gemm(
    const u16* __restrict__ A, const u16* __restrict__ Bt,
    const float* __restrict__ bias, const float* __restrict__ res,
    float* __restrict__ Cf, __hip_bfloat16* __restrict__ Cb,
    int M, int N, int K)
{
    __shared__ u16 As[128 * 64];
    __shared__ u16 Bs[128 * 64];
    const int tid = threadIdx.x;
    const int wid = tid >> 6, lane = tid & 63;
    const int m0 = blockIdx.y * 128, n0 = blockIdx.x * 128;
    const int srow = tid >> 3;          // 0..31 within staging group
    const int selem = (tid & 7) << 3;   // element offset 0..56 (16B chunks)
    const int wm = (wid >> 1) * 64, wn = (wid & 1) * 64;

    f32x4 acc[4][4] = {};

    for (int kt = 0; kt < K; kt += 64) {
        __syncthreads();
        #pragma unroll
        for (int g = 0; g < 4; ++g) {
            int r = g * 32 + srow;
            int gr = m0 + r; if (gr > M - 1) gr = M - 1;
            async_copy16(&As[r * 64 + selem], A + (size_t)gr * K + kt + selem);
            async_copy16(&Bs[r * 64 + selem], Bt + (size_t)(n0 + r) * K + kt + selem);
        }
        __syncthreads();
        #pragma unroll
        for (int ks = 0; ks < 64; ks += 32) {
            const int kk = ks + ((lane >> 4) << 3);
            bf16x8 af[4], bfr[4];
            #pragma unroll
            for (int i = 0; i < 4; ++i)
                af[i] = *(const bf16x8*)&As[(wm + i * 16 + (lane & 15)) * 64 + kk];
            #pragma unroll
            for (int j = 0; j < 4; ++j)
                bfr[j] = *(const bf16x8*)&Bs[(wn + j * 16 + (lane & 15)) * 64 + kk];
            #pragma unroll
            for (int i = 0; i < 4; ++i)
                #pragma unroll
                for (int j = 0; j < 4; ++j)
                    acc[i][j] = __builtin_amdgcn_mfma_f32_16x16x32_bf16(af[i], bfr[j], acc[i][j], 0, 0, 0);
        }
    }
    const int cl = lane & 15, rg = (lane >> 4) << 2;
    #pragma unroll
    for (int i = 0; i < 4; ++i) {
        #pragma unroll
        for (int j = 0; j < 4; ++j) {
            const int col = n0 + wn + j * 16 + cl;
            const float bv = bias[col];
            #pragma unroll
            for (int r = 0; r < 4; ++r) {
                const int row = m0 + wm + i * 16 + rg + r;
                if (row >= M) continue;
                float v = acc[i][j][r] + bv;
                if (RES) v += res[(size_t)row * N + col];
                if (GELU) v = 0.5f * v * (1.0f + erff(v * 0.70710678118f));
                if (BF16OUT) Cb[(size_t)row * N + col] = __float2bfloat16(v);
                else         Cf[(size_t)row * N + col] = v;
            }
        }
    }
}

// ---------------------------------------------------------------- assemble tokens: cls + patches + pos (fp32)
__global__ void k_assemble(const float* __restrict__ ptmp, const float* __restrict__ cls_tok,
                           const float* __restrict__ pos, float* __restrict__ tok) {
    int idx = blockIdx.x * 256 + threadIdx.x;   // < 16*197*384
    int d = idx % 384;
    int t = (idx / 384) % 197;
    int b = idx / (384 * 197);
    float v = (t == 0) ? cls_tok[d] : ptmp[((size_t)b * 196 + t - 1) * 384 + d];
    tok[idx] = v + pos[t * 384 + d];
}

// ---------------------------------------------------------------- layernorm (fp32 compute), OT output
template<typename OT>
__global__ __launch_bounds__(256) void k_ln(const float* __restrict__ X, const float* __restrict__ s,
                                            const float* __restrict__ bb, OT* __restrict__ Y, int rows) {
    int wid = threadIdx.x >> 6, lane = threadIdx.x & 63;
    int row = blockIdx.x * 4 + wid;
    if (row >= rows) return;
    const float* x = X + (size_t)row * 384;
    float v[6], sum = 0.f, sq = 0.f;
    #pragma unroll
    for (int i = 0; i < 6; ++i) { float t = x[lane + 64 * i]; v[i] = t; sum += t; sq += t * t; }
    #pragma unroll
    for (int m = 32; m > 0; m >>= 1) { sum += __shfl_xor(sum, m); sq += __shfl_xor(sq, m); }
    float mean = sum * (1.f / 384.f);
    float var  = sq * (1.f / 384.f) - mean * mean;
    float rstd = rsqrtf(var + 1e-6f);
    OT* y = Y + (size_t)row * 384;
    #pragma unroll
    for (int i = 0; i < 6; ++i) {
        int d = lane + 64 * i;
        float o = (v[i] - mean) * rstd * s[d] + bb[d];
        y[d] = (OT)o;
    }
}

// ---------------------------------------------------------------- MFMA attention
// qkv: bf16 (B*197, 1152) rows [Q|K|V]; o: bf16 (B*197, 384).
// grid (96, 2): block = (b,h) x q-tile-half. 4 waves, each wave owns 16-query tiles.
__global__ __launch_bounds__(256) void k_attn_mfma(const u16* __restrict__ qkv, u16* __restrict__ o) {
    __shared__ u16 Ks[208 * 64];       // K rows, XOR-swizzled 16B chunks
    __shared__ u16 VT[64 * 256];       // V^T rows (d, k), swizzled, tail-zeroed
    __shared__ u16 Pl[4][16 * 256];    // per-wave P tile (q_local, k), swizzled
    const int bh = blockIdx.x;
    const int b = bh / 6, hh = bh % 6;
    const u16* base = qkv + (size_t)b * 197 * 1152 + hh * 64;
    const int tid = threadIdx.x, wid = tid >> 6, lane = tid & 63;

    // zero-fill tails (disjoint from staged data; single barrier below)
    for (int i = tid; i < 64 * 59; i += 256) {
        int d = i / 59, k = 197 + i % 59;
        VT[d * 256 + (k ^ ((d & 7) << 3))] = 0;
    }
    for (int i = tid; i < 64 * 48; i += 256) {
        int q = i / 48, k = 208 + i % 48;     // q = w*16 + q_local
        Pl[q >> 4][(q & 15) * 256 + (k ^ ((q & 7) << 3))] = 0;
    }
    // stage K rows (197 x 64) as 16B chunks
    for (int i = tid; i < 197 * 8; i += 256) {
        int r = i >> 3, cc = (i & 7) << 3;
        uint4 v = *(const uint4*)(base + (size_t)r * 1152 + 384 + cc);
        *(uint4*)&Ks[r * 64 + (cc ^ ((r & 7) << 3))] = v;
    }
    // stage V transposed: VT[d][k]
    for (int i = tid; i < 197 * 8; i += 256) {
        int r = i >> 3, d0 = (i & 7) << 3;
        uint4 v = *(const uint4*)(base + (size_t)r * 1152 + 768 + d0);
        const u16* pv = (const u16*)&v;
        #pragma unroll
        for (int j = 0; j < 8; ++j) {
            int d = d0 + j;
            VT[d * 256 + (r ^ ((d & 7) << 3))] = pv[j];
        }
    }
    __syncthreads();

    const int g = lane >> 4, c = lane & 15;
    const int t0 = blockIdx.y * 7;
    const int nt = blockIdx.y ? 6 : 7;
    for (int t = wid; t < nt; t += 4) {
        const int qt = t0 + t;
        const int q0 = qt * 16;
        int qrow = q0 + c; if (qrow > 196) qrow = 196;
        bf16x8 aq[2];
        aq[0] = *(const bf16x8*)(base + (size_t)qrow * 1152 + g * 8);
        aq[1] = *(const bf16x8*)(base + (size_t)qrow * 1152 + 32 + g * 8);

        f32x4 acc[13] = {};
        #pragma unroll
        for (int j = 0; j < 13; ++j) {
            int kr = j * 16 + c;
            bf16x8 b0 = *(const bf16x8*)&Ks[kr * 64 + ((g * 8) ^ ((kr & 7) << 3))];
            bf16x8 b1 = *(const bf16x8*)&Ks[kr * 64 + ((32 + g * 8) ^ ((kr & 7) << 3))];
            acc[j] = __builtin_amdgcn_mfma_f32_16x16x32_bf16(aq[0], b0, acc[j], 0, 0, 0);
            acc[j] = __builtin_amdgcn_mfma_f32_16x16x32_bf16(aq[1], b1, acc[j], 0, 0, 0);
        }

        // masked softmax over k (cols), fp32; rows q0+g*4+r live in 16-lane groups
        float sc[13][4];
        float mr[4] = {-1e30f, -1e30f, -1e30f, -1e30f};
        #pragma unroll
        for (int j = 0; j < 13; ++j) {
            bool valid = (j * 16 + c) < 197;
            #pragma unroll
            for (int r = 0; r < 4; ++r) {
                float v = valid ? acc[j][r] * 0.125f : -1e30f;
                sc[j][r] = v;
                mr[r] = fmaxf(mr[r], v);
            }
        }
        #pragma unroll
        for (int r = 0; r < 4; ++r) {
            #pragma unroll
            for (int msk = 1; msk <= 8; msk <<= 1) mr[r] = fmaxf(mr[r], __shfl_xor(mr[r], msk));
        }
        float lr[4] = {0.f, 0.f, 0.f, 0.f};
        #pragma unroll
        for (int j = 0; j < 13; ++j)
            #pragma unroll
            for (int r = 0; r < 4; ++r) { float e = __expf(sc[j][r] - mr[r]); sc[j][r] = e; lr[r] += e; }
        #pragma unroll
        for (int r = 0; r < 4; ++r) {
            #pragma unroll
            for (int msk = 1; msk <= 8; msk <<= 1) lr[r] += __shfl_xor(lr[r], msk);
            lr[r] = 1.f / lr[r];
        }
        // P -> per-wave LDS (bf16, swizzled)
        #pragma unroll
        for (int j = 0; j < 13; ++j) {
            int col = j * 16 + c;
            #pragma unroll
            for (int r = 0; r < 4; ++r) {
                int q = g * 4 + r;
                Pl[wid][q * 256 + (col ^ ((q & 7) << 3))] = f2b(sc[j][r] * lr[r]);
            }
        }
        asm volatile("s_waitcnt lgkmcnt(0)" ::: "memory");   // wave-private tile, no barrier

        // O = P @ V^T
        f32x4 av[4] = {};
        #pragma unroll
        for (int ks = 0; ks < 7; ++ks) {
            int kk = ks * 32 + g * 8;
            bf16x8 ap = *(const bf16x8*)&Pl[wid][c * 256 + (kk ^ ((c & 7) << 3))];
            #pragma unroll
            for (int jd = 0; jd < 4; ++jd) {
                int dr = jd * 16 + c;
                bf16x8 bv = *(const bf16x8*)&VT[dr * 256 + (kk ^ ((dr & 7) << 3))];
                av[jd] = __builtin_amdgcn_mfma_f32_16x16x32_bf16(ap, bv, av[jd], 0, 0, 0);
            }
        }
        #pragma unroll
        for (int jd = 0; jd < 4; ++jd) {
            #pragma unroll
            for (int r = 0; r < 4; ++r) {
                int q = q0 + g * 4 + r;
                if (q < 197)
                    o[((size_t)b * 197 + q) * 384 + hh * 64 + jd * 16 + c] = f2b(av[jd][r]);
            }
        }
    }
}

// ---------------------------------------------------------------- cls output (fp32)
__global__ void k_clsout(const float* __restrict__ tokn, float* __restrict__ out) {
    int idx = blockIdx.x * 256 + threadIdx.x;   // < 6144
    int b = idx / 384, d = idx % 384;
    out[idx] = tokn[(size_t)b * 197 * 384 + d];
}

// ---------------------------------------------------------------- feature normalize -> bf16 (B*196, 384)
__global__ __launch_bounds__(256) void k_fn(const float* __restrict__ tokn, __hip_bfloat16* __restrict__ fn) {
    int wid = threadIdx.x >> 6, lane = threadIdx.x & 63;
    int row = blockIdx.x * 4 + wid;   // < 3136
    int b = row / 196, n = row % 196;
    const float* xr = tokn + ((size_t)b * 197 + 1 + n) * 384;
    const float* cr = tokn + (size_t)b * 197 * 384;
    float v[6], ss = 0.f;
    #pragma unroll
    for (int i = 0; i < 6; ++i) {
        int d = lane + 64 * i;
        float t = xr[d] - cr[d];
        v[i] = t; ss += t * t;
    }
    #pragma unroll
    for (int m = 32; m > 0; m >>= 1) ss += __shfl_xor(ss, m);
    float inv = 1.f / fmaxf(sqrtf(ss), 1e-12f);
    #pragma unroll
    for (int i = 0; i < 6; ++i) fn[(size_t)row * 384 + lane + 64 * i] = __float2bfloat16(v[i] * inv);
}

// ---------------------------------------------------------------- proto normalize + transpose -> bf16 (8000, 384)
__global__ __launch_bounds__(256) void k_pn(const float* __restrict__ proto, __hip_bfloat16* __restrict__ pn) {
    int p = blockIdx.x;
    int k = threadIdx.x >> 6, lane = threadIdx.x & 63;
    float v[6], ss = 0.f;
    #pragma unroll
    for (int i = 0; i < 6; ++i) {
        int d = lane + 64 * i;
        float t = proto[((size_t)p * 384 + d) * 4 + k];
        v[i] = t; ss += t * t;
    }
    #pragma unroll
    for (int m = 32; m > 0; m >>= 1) ss += __shfl_xor(ss, m);
    float inv = 1.f / fmaxf(sqrtf(ss), 1e-12f);
    #pragma unroll
    for (int i = 0; i < 6; ++i) pn[((size_t)p * 4 + k) * 384 + lane + 64 * i] = __float2bfloat16(v[i] * inv);
}

// ---------------------------------------------------------------- top4 helper
__device__ __forceinline__ void top4_insert(float v, float& t0, float& t1, float& t2, float& t3) {
    if (v > t3) {
        t3 = v;
        if (t3 > t2) { float t = t2; t2 = t3; t3 = t; }
        if (t2 > t1) { float t = t1; t1 = t2; t2 = t; }
        if (t1 > t0) { float t = t0; t0 = t1; t1 = t; }
    }
}

// ---------------------------------------------------------------- dist: bf16 MFMA GEMM + fused top-4 + score
__global__ __launch_bounds__(256) void k_dist_mfma(
    const __hip_bfloat16* __restrict__ fnb, const __hip_bfloat16* __restrict__ pnb,
    const float* __restrict__ psel, float* __restrict__ out)
{
    __shared__ u16 Ap[128 * 64];
    __shared__ u16 Bf[208 * 64];
    const u16* fn = (const u16*)fnb;
    const u16* pn = (const u16*)pnb;
    const int b = blockIdx.x;
    const int pb = blockIdx.y;
    const int tid = threadIdx.x, wid = tid >> 6, lane = tid & 63;
    const int srow = tid >> 3;
    const int selem = (tid & 7) << 3;

    f32x4 acc[2][13] = {};

    for (int kt = 0; kt < 384; kt += 64) {
        uint4 ar[4], br[7];
        #pragma unroll
        for (int g = 0; g < 4; ++g) {
            int r = g * 32 + srow;
            int gr = pb * 128 + r; if (gr > 7999) gr = 7999;
            ar[g] = *(const uint4*)(pn + (size_t)gr * 384 + kt + selem);
        }
        #pragma unroll
        for (int g = 0; g < 7; ++g) {
            int r = g * 32 + srow;
            int fr = r > 195 ? 195 : r;
            br[g] = *(const uint4*)(fn + ((size_t)b * 196 + fr) * 384 + kt + selem);
        }
        __syncthreads();
        #pragma unroll
        for (int g = 0; g < 4; ++g) {
            int r = g * 32 + srow;
            *(uint4*)&Ap[r * 64 + (selem ^ ((r & 7) << 3))] = ar[g];
        }
        #pragma unroll
        for (int g = 0; g < 7; ++g) {
            int r = g * 32 + srow;
            if (r < 208) *(uint4*)&Bf[r * 64 + (selem ^ ((r & 7) << 3))] = br[g];
        }
        __syncthreads();
        #pragma unroll
        for (int ks = 0; ks < 64; ks += 32) {
            const int kk = ks + ((lane >> 4) << 3);
            bf16x8 af[2];
            #pragma unroll
            for (int i = 0; i < 2; ++i) {
                int r = wid * 32 + i * 16 + (lane & 15);
                af[i] = *(const bf16x8*)&Ap[r * 64 + (kk ^ ((r & 7) << 3))];
            }
            #pragma unroll
            for (int j = 0; j < 13; ++j) {
                int r = j * 16 + (lane & 15);
                bf16x8 bj = *(const bf16x8*)&Bf[r * 64 + (kk ^ ((r & 7) << 3))];
                acc[0][j] = __builtin_amdgcn_mfma_f32_16x16x32_bf16(af[0], bj, acc[0][j], 0, 0, 0);
                acc[1][j] = __builtin_amdgcn_mfma_f32_16x16x32_bf16(af[1], bj, acc[1][j], 0, 0, 0);
            }
        }
    }
    const int cl = lane & 15;
    #pragma unroll
    for (int mi = 0; mi < 2; ++mi) {
        float t0 = -1e30f, t1 = -1e30f, t2 = -1e30f, t3 = -1e30f;
        #pragma unroll
        for (int j = 0; j < 13; ++j) {
            if (j * 16 + cl >= 196) continue;
            #pragma unroll
            for (int r = 0; r < 4; ++r) top4_insert(acc[mi][j][r], t0, t1, t2, t3);
        }
        #pragma unroll
        for (int m = 1; m <= 8; m <<= 1) {
            float u0 = __shfl_xor(t0, m), u1 = __shfl_xor(t1, m);
            float u2 = __shfl_xor(t2, m), u3 = __shfl_xor(t3, m);
            top4_insert(u0, t0, t1, t2, t3);
            top4_insert(u1, t0, t1, t2, t3);
            top4_insert(u2, t0, t1, t2, t3);
            top4_insert(u3, t0, t1, t2, t3);
        }
        if (cl == 0) {
            int proto = pb * 32 + wid * 8 + mi * 4 + (lane >> 4);
            if (proto < 2000) {
                float sl[4], fac = 1e-10f;
                #pragma unroll
                for (int i = 0; i < 4; ++i) {
                    sl[i] = 1.f / (1.f + expf(-psel[proto * 4 + i] * 100.f));
                    fac += sl[i];
                }
                float score = (t0 * sl[0] + t1 * sl[1] + t2 * sl[2] + t3 * sl[3]) * 4.f / fac;
                out[6144 + (size_t)b * 2000 + proto] = score;
            }
        }
    }
}

// ---------------------------------------------------------------- host launcher
extern "C" void kernel_launch(void* const* d_in, const int* in_sizes, int n_in,
                              void* d_out, int out_size, void* d_ws, size_t ws_size,
                              hipStream_t stream) {
    const float* x       = (const float*)d_in[0];
    const float* patch_w = (const float*)d_in[1];
    const float* patch_b = (const float*)d_in[2];
    const float* cls_tok = (const float*)d_in[3];
    const float* pos     = (const float*)d_in[4];
    const float* ln1_s   = (const float*)d_in[5];
    const float* ln1_b   = (const float*)d_in[6];
    const float* qkv_w   = (const float*)d_in[7];
    const float* qkv_b   = (const float*)d_in[8];
    const float* proj_w  = (const float*)d_in[9];
    const float* proj_b  = (const float*)d_in[10];
    const float* ln2_s   = (const float*)d_in[11];
    const float* ln2_b   = (const float*)d_in[12];
    const float* fc1_w   = (const float*)d_in[13];
    const float* fc1_b   = (const float*)d_in[14];
    const float* fc2_w   = (const float*)d_in[15];
    const float* fc2_b   = (const float*)d_in[16];
    const float* norm_s  = (const float*)d_in[17];
    const float* norm_b  = (const float*)d_in[18];
    const float* proto   = (const float*)d_in[19];
    const float* psel    = (const float*)d_in[20];
    float* out = (float*)d_out;
    char* w = (char*)d_ws;

    __hip_bfloat16* wPb  = (__hip_bfloat16*)(w);             // 589824
    __hip_bfloat16* wQ   = (__hip_bfloat16*)(w + 589824);    // 5308416
    __hip_bfloat16* wPr  = (__hip_bfloat16*)(w + 5898240);   // 1769472
    __hip_bfloat16* wF1  = (__hip_bfloat16*)(w + 7667712);   // 7077888
    __hip_bfloat16* wF2  = (__hip_bfloat16*)(w + 14745600);  // 7077888
    __hip_bfloat16* Acol = (__hip_bfloat16*)(w + 21823488);  // 4816896
    float*          ptmp = (float*)         (w + 26640384);  // 4816896
    float*          tok  = (float*)         (w + 31457280);  // 4841472
    __hip_bfloat16* hbf  = (__hip_bfloat16*)(w + 36298752);  // 2420736
    __hip_bfloat16* qkvb = (__hip_bfloat16*)(w + 38719488);  // 7262208 (bf16 now)
    __hip_bfloat16* aob  = (__hip_bfloat16*)(w + 53243904);  // 2420736
    __hip_bfloat16* hbig = (__hip_bfloat16*)(w + 55664640);  // 9682944
    float*          hf   = (float*)         (w + 65347584);  // 4841472
    __hip_bfloat16* fnb  = (__hip_bfloat16*)(w + 70189056);  // 2408448
    __hip_bfloat16* pnb  = (__hip_bfloat16*)(w + 72597504);  // 6144000

    k_cvt<<<1152, 256, 0, stream>>>(patch_w, wPb, 294912);
    k_wt<<<dim3(36, 12, 6), 256, 0, stream>>>(qkv_w, wQ, 384, 1152);
    k_wt<<<dim3(12, 12, 6), 256, 0, stream>>>(proj_w, wPr, 384, 384);
    k_wt<<<dim3(48, 12, 6), 256, 0, stream>>>(fc1_w, wF1, 384, 1536);
    k_wt<<<dim3(12, 48, 6), 256, 0, stream>>>(fc2_w, wF2, 1536, 384);

    k_im2col<<<9408, 256, 0, stream>>>(x, Acol);
    k_mfma_gemm<0,0,0><<<dim3(3, 25), 256, 0, stream>>>(
        (const u16*)Acol, (const u16*)wPb, patch_b, nullptr, ptmp, nullptr, 3136, 384, 768);
    k_assemble<<<4728, 256, 0, stream>>>(ptmp, cls_tok, pos, tok);

    for (int l = 0; l < 6; ++l) {
        k_ln<__hip_bfloat16><<<788, 256, 0, stream>>>(tok, ln1_s + l * 384, ln1_b + l * 384, hbf, MROWS);
        k_mfma_gemm<0,0,1><<<dim3(9, 25), 256, 0, stream>>>(
            (const u16*)hbf, (const u16*)(wQ + (size_t)l * 1152 * 384), qkv_b + l * 1152,
            nullptr, nullptr, qkvb, MROWS, 1152, 384);
        k_attn_mfma<<<dim3(96, 2), 256, 0, stream>>>((const u16*)qkvb, (u16*)aob);
        k_mfma_gemm<1,0,0><<<dim3(3, 25), 256, 0, stream>>>(
            (const u16*)aob, (const u16*)(wPr + (size_t)l * 384 * 384), proj_b + l * 384,
            tok, tok, nullptr, MROWS, 384, 384);
        k_ln<__hip_bfloat16><<<788, 256, 0, stream>>>(tok, ln2_s + l * 384, ln2_b + l * 384, hbf, MROWS);
        k_mfma_gemm<0,1,1><<<dim3(12, 25), 256, 0, stream>>>(
            (const u16*)hbf, (const u16*)(wF1 + (size_t)l * 1536 * 384), fc1_b + l * 1536,
            nullptr, nullptr, hbig, MROWS, 1536, 384);
        k_mfma_gemm<1,0,0><<<dim3(3, 25), 256, 0, stream>>>(
            (const u16*)hbig, (const u16*)(wF2 + (size_t)l * 384 * 1536), fc2_b + l * 384,
            tok, tok, nullptr, MROWS, 384, 1536);
    }

    k_ln<float><<<788, 256, 0, stream>>>(tok, norm_s, norm_b, hf, MROWS);
    k_clsout<<<24, 256, 0, stream>>>(hf, out);
    k_fn<<<784, 256, 0, stream>>>(hf, fnb);
    k_pn<<<2000, 256, 0, stream>>>(proto, pnb);
    k_dist_mfma<<<dim3(16, 63), 256, 0, stream>>>(fnb, pnb, psel, out);
}

// Round 4
// 766.734 us; speedup vs baseline: 3.9002x; 1.2848x over previous
//
#include <hip/hip_runtime.h>
#include <hip/hip_bf16.h>
#include <math.h>

// ProtoViT forward: bf16-MFMA GEMMs + MFMA attention + fp32 residual/LN path.
// B=16, D=384, DEPTH=6, H=6, HD=64, P=2000, NP=4, N=196, T=197.

#define MROWS 3152   // 16*197

typedef short bf16x8 __attribute__((ext_vector_type(8)));
typedef float f32x4 __attribute__((ext_vector_type(4)));
typedef unsigned short u16;

__device__ __forceinline__ void async_copy16(void* lds, const void* g) {
    __builtin_amdgcn_global_load_lds((const __attribute__((address_space(1))) unsigned int*)g,
                                     (__attribute__((address_space(3))) unsigned int*)lds,
                                     16, 0, 0);
}

__device__ __forceinline__ u16 f2b(float x) {
    __hip_bfloat16 h = __float2bfloat16(x);
    return *(u16*)&h;
}

// ---------------------------------------------------------------- fp32 -> bf16 elementwise
__global__ void k_cvt(const float* __restrict__ in, __hip_bfloat16* __restrict__ o, int n) {
    int i = blockIdx.x * 256 + threadIdx.x;
    if (i < n) o[i] = __float2bfloat16(in[i]);
}

// ---------------------------------------------------------------- weight transpose (K,N) f32 -> (N,K) bf16, per layer z
__global__ __launch_bounds__(256) void k_wt(const float* __restrict__ W, __hip_bfloat16* __restrict__ Wt,
                                            int K, int N) {
    __shared__ float t[32][33];
    const float* src = W + (size_t)blockIdx.z * K * N;
    __hip_bfloat16* dst = Wt + (size_t)blockIdx.z * K * N;
    int n0 = blockIdx.x * 32, k0 = blockIdx.y * 32;
    int tx = threadIdx.x & 31, ty = threadIdx.x >> 5;   // 32 x 8
    #pragma unroll
    for (int i = 0; i < 4; ++i) t[ty + i * 8][tx] = src[(size_t)(k0 + ty + i * 8) * N + n0 + tx];
    __syncthreads();
    #pragma unroll
    for (int i = 0; i < 4; ++i)
        dst[(size_t)(n0 + ty + i * 8) * K + k0 + tx] = __float2bfloat16(t[tx][ty + i * 8]);
}

// ---------------------------------------------------------------- im2col -> bf16 (B*196, 768)
__global__ void k_im2col(const float* __restrict__ x, __hip_bfloat16* __restrict__ Acol) {
    int idx = blockIdx.x * 256 + threadIdx.x;    // < 3136*768
    int k = idx % 768;
    int m = idx / 768;
    int b = m / 196, n = m % 196;
    int c = k >> 8, rem = k & 255, i = rem >> 4, j = rem & 15;
    int py = n / 14, px = n % 14;
    Acol[idx] = __float2bfloat16(x[((b * 3 + c) * 224 + py * 16 + i) * 224 + px * 16 + j]);
}

// ---------------------------------------------------------------- bf16 MFMA GEMM, 128x128 tile
template<int RES, int GELU, int BF16OUT>
__global__ __launch_bounds__(256) void k_mfma_gemm(
    const u16* __restrict__ A, const u16* __restrict__ Bt,
    const float* __restrict__ bias, const float* __restrict__ res,
    float* __restrict__ Cf, __hip_bfloat16* __restrict__ Cb,
    int M, int N, int K)
{
    __shared__ u16 As[128 * 64];
    __shared__ u16 Bs[128 * 64];
    const int tid = threadIdx.x;
    const int wid = tid >> 6, lane = tid & 63;
    const int m0 = blockIdx.y * 128, n0 = blockIdx.x * 128;
    const int srow = tid >> 3;          // 0..31 within staging group
    const int selem = (tid & 7) << 3;   // element offset 0..56 (16B chunks)
    const int wm = (wid >> 1) * 64, wn = (wid & 1) * 64;

    f32x4 acc[4][4] = {};

    for (int kt = 0; kt < K; kt += 64) {
        __syncthreads();
        #pragma unroll
        for (int g = 0; g < 4; ++g) {
            int r = g * 32 + srow;
            int gr = m0 + r; if (gr > M - 1) gr = M - 1;
            async_copy16(&As[r * 64 + selem], A + (size_t)gr * K + kt + selem);
            async_copy16(&Bs[r * 64 + selem], Bt + (size_t)(n0 + r) * K + kt + selem);
        }
        __syncthreads();
        #pragma unroll
        for (int ks = 0; ks < 64; ks += 32) {
            const int kk = ks + ((lane >> 4) << 3);
            bf16x8 af[4], bfr[4];
            #pragma unroll
            for (int i = 0; i < 4; ++i)
                af[i] = *(const bf16x8*)&As[(wm + i * 16 + (lane & 15)) * 64 + kk];
            #pragma unroll
            for (int j = 0; j < 4; ++j)
                bfr[j] = *(const bf16x8*)&Bs[(wn + j * 16 + (lane & 15)) * 64 + kk];
            #pragma unroll
            for (int i = 0; i < 4; ++i)
                #pragma unroll
                for (int j = 0; j < 4; ++j)
                    acc[i][j] = __builtin_amdgcn_mfma_f32_16x16x32_bf16(af[i], bfr[j], acc[i][j], 0, 0, 0);
        }
    }
    const int cl = lane & 15, rg = (lane >> 4) << 2;
    #pragma unroll
    for (int i = 0; i < 4; ++i) {
        #pragma unroll
        for (int j = 0; j < 4; ++j) {
            const int col = n0 + wn + j * 16 + cl;
            const float bv = bias[col];
            #pragma unroll
            for (int r = 0; r < 4; ++r) {
                const int row = m0 + wm + i * 16 + rg + r;
                if (row >= M) continue;
                float v = acc[i][j][r] + bv;
                if (RES) v += res[(size_t)row * N + col];
                if (GELU) v = 0.5f * v * (1.0f + erff(v * 0.70710678118f));
                if (BF16OUT) Cb[(size_t)row * N + col] = __float2bfloat16(v);
                else         Cf[(size_t)row * N + col] = v;
            }
        }
    }
}

// ---------------------------------------------------------------- bf16 MFMA GEMM, 128x64 tile (small-N occupancy)
// 4 waves stacked in M: wave = 32 rows x 64 cols, acc[2][4] = 32 VGPR.
template<int RES, int GELU, int BF16OUT>
__global__ __launch_bounds__(256) void k_mfma_gemm64(
    const u16* __restrict__ A, const u16* __restrict__ Bt,
    const float* __restrict__ bias, const float* __restrict__ res,
    float* __restrict__ Cf, __hip_bfloat16* __restrict__ Cb,
    int M, int N, int K)
{
    __shared__ u16 As[128 * 64];
    __shared__ u16 Bs[64 * 64];
    const int tid = threadIdx.x;
    const int wid = tid >> 6, lane = tid & 63;
    const int m0 = blockIdx.y * 128, n0 = blockIdx.x * 64;
    const int srow = tid >> 3;
    const int selem = (tid & 7) << 3;
    const int wm = wid * 32;

    f32x4 acc[2][4] = {};

    for (int kt = 0; kt < K; kt += 64) {
        __syncthreads();
        #pragma unroll
        for (int g = 0; g < 4; ++g) {
            int r = g * 32 + srow;
            int gr = m0 + r; if (gr > M - 1) gr = M - 1;
            async_copy16(&As[r * 64 + selem], A + (size_t)gr * K + kt + selem);
        }
        #pragma unroll
        for (int g = 0; g < 2; ++g) {
            int r = g * 32 + srow;
            async_copy16(&Bs[r * 64 + selem], Bt + (size_t)(n0 + r) * K + kt + selem);
        }
        __syncthreads();
        #pragma unroll
        for (int ks = 0; ks < 64; ks += 32) {
            const int kk = ks + ((lane >> 4) << 3);
            bf16x8 af[2], bfr[4];
            #pragma unroll
            for (int i = 0; i < 2; ++i)
                af[i] = *(const bf16x8*)&As[(wm + i * 16 + (lane & 15)) * 64 + kk];
            #pragma unroll
            for (int j = 0; j < 4; ++j)
                bfr[j] = *(const bf16x8*)&Bs[(j * 16 + (lane & 15)) * 64 + kk];
            #pragma unroll
            for (int i = 0; i < 2; ++i)
                #pragma unroll
                for (int j = 0; j < 4; ++j)
                    acc[i][j] = __builtin_amdgcn_mfma_f32_16x16x32_bf16(af[i], bfr[j], acc[i][j], 0, 0, 0);
        }
    }
    const int cl = lane & 15, rg = (lane >> 4) << 2;
    #pragma unroll
    for (int i = 0; i < 2; ++i) {
        #pragma unroll
        for (int j = 0; j < 4; ++j) {
            const int col = n0 + j * 16 + cl;
            const float bv = bias[col];
            #pragma unroll
            for (int r = 0; r < 4; ++r) {
                const int row = m0 + wm + i * 16 + rg + r;
                if (row >= M) continue;
                float v = acc[i][j][r] + bv;
                if (RES) v += res[(size_t)row * N + col];
                if (GELU) v = 0.5f * v * (1.0f + erff(v * 0.70710678118f));
                if (BF16OUT) Cb[(size_t)row * N + col] = __float2bfloat16(v);
                else         Cf[(size_t)row * N + col] = v;
            }
        }
    }
}

// ---------------------------------------------------------------- assemble tokens: cls + patches + pos (fp32)
__global__ void k_assemble(const float* __restrict__ ptmp, const float* __restrict__ cls_tok,
                           const float* __restrict__ pos, float* __restrict__ tok) {
    int idx = blockIdx.x * 256 + threadIdx.x;   // < 16*197*384
    int d = idx % 384;
    int t = (idx / 384) % 197;
    int b = idx / (384 * 197);
    float v = (t == 0) ? cls_tok[d] : ptmp[((size_t)b * 196 + t - 1) * 384 + d];
    tok[idx] = v + pos[t * 384 + d];
}

// ---------------------------------------------------------------- layernorm (fp32 compute), OT output
template<typename OT>
__global__ __launch_bounds__(256) void k_ln(const float* __restrict__ X, const float* __restrict__ s,
                                            const float* __restrict__ bb, OT* __restrict__ Y, int rows) {
    int wid = threadIdx.x >> 6, lane = threadIdx.x & 63;
    int row = blockIdx.x * 4 + wid;
    if (row >= rows) return;
    const float* x = X + (size_t)row * 384;
    float v[6], sum = 0.f, sq = 0.f;
    #pragma unroll
    for (int i = 0; i < 6; ++i) { float t = x[lane + 64 * i]; v[i] = t; sum += t; sq += t * t; }
    #pragma unroll
    for (int m = 32; m > 0; m >>= 1) { sum += __shfl_xor(sum, m); sq += __shfl_xor(sq, m); }
    float mean = sum * (1.f / 384.f);
    float var  = sq * (1.f / 384.f) - mean * mean;
    float rstd = rsqrtf(var + 1e-6f);
    OT* y = Y + (size_t)row * 384;
    #pragma unroll
    for (int i = 0; i < 6; ++i) {
        int d = lane + 64 * i;
        float o = (v[i] - mean) * rstd * s[d] + bb[d];
        y[d] = (OT)o;
    }
}

// ---------------------------------------------------------------- MFMA attention
__global__ __launch_bounds__(256) void k_attn_mfma(const u16* __restrict__ qkv, u16* __restrict__ o) {
    __shared__ u16 Ks[208 * 64];       // K rows, XOR-swizzled 16B chunks
    __shared__ u16 VT[64 * 256];       // V^T rows (d, k), swizzled, tail-zeroed
    __shared__ u16 Pl[4][16 * 256];    // per-wave P tile (q_local, k), swizzled
    const int bh = blockIdx.x;
    const int b = bh / 6, hh = bh % 6;
    const u16* base = qkv + (size_t)b * 197 * 1152 + hh * 64;
    const int tid = threadIdx.x, wid = tid >> 6, lane = tid & 63;

    for (int i = tid; i < 64 * 59; i += 256) {
        int d = i / 59, k = 197 + i % 59;
        VT[d * 256 + (k ^ ((d & 7) << 3))] = 0;
    }
    for (int i = tid; i < 64 * 48; i += 256) {
        int q = i / 48, k = 208 + i % 48;
        Pl[q >> 4][(q & 15) * 256 + (k ^ ((q & 7) << 3))] = 0;
    }
    for (int i = tid; i < 197 * 8; i += 256) {
        int r = i >> 3, cc = (i & 7) << 3;
        uint4 v = *(const uint4*)(base + (size_t)r * 1152 + 384 + cc);
        *(uint4*)&Ks[r * 64 + (cc ^ ((r & 7) << 3))] = v;
    }
    for (int i = tid; i < 197 * 8; i += 256) {
        int r = i >> 3, d0 = (i & 7) << 3;
        uint4 v = *(const uint4*)(base + (size_t)r * 1152 + 768 + d0);
        const u16* pv = (const u16*)&v;
        #pragma unroll
        for (int j = 0; j < 8; ++j) {
            int d = d0 + j;
            VT[d * 256 + (r ^ ((d & 7) << 3))] = pv[j];
        }
    }
    __syncthreads();

    const int g = lane >> 4, c = lane & 15;
    const int t0 = blockIdx.y * 7;
    const int nt = blockIdx.y ? 6 : 7;
    for (int t = wid; t < nt; t += 4) {
        const int qt = t0 + t;
        const int q0 = qt * 16;
        int qrow = q0 + c; if (qrow > 196) qrow = 196;
        bf16x8 aq[2];
        aq[0] = *(const bf16x8*)(base + (size_t)qrow * 1152 + g * 8);
        aq[1] = *(const bf16x8*)(base + (size_t)qrow * 1152 + 32 + g * 8);

        f32x4 acc[13] = {};
        #pragma unroll
        for (int j = 0; j < 13; ++j) {
            int kr = j * 16 + c;
            bf16x8 b0 = *(const bf16x8*)&Ks[kr * 64 + ((g * 8) ^ ((kr & 7) << 3))];
            bf16x8 b1 = *(const bf16x8*)&Ks[kr * 64 + ((32 + g * 8) ^ ((kr & 7) << 3))];
            acc[j] = __builtin_amdgcn_mfma_f32_16x16x32_bf16(aq[0], b0, acc[j], 0, 0, 0);
            acc[j] = __builtin_amdgcn_mfma_f32_16x16x32_bf16(aq[1], b1, acc[j], 0, 0, 0);
        }

        float sc[13][4];
        float mr[4] = {-1e30f, -1e30f, -1e30f, -1e30f};
        #pragma unroll
        for (int j = 0; j < 13; ++j) {
            bool valid = (j * 16 + c) < 197;
            #pragma unroll
            for (int r = 0; r < 4; ++r) {
                float v = valid ? acc[j][r] * 0.125f : -1e30f;
                sc[j][r] = v;
                mr[r] = fmaxf(mr[r], v);
            }
        }
        #pragma unroll
        for (int r = 0; r < 4; ++r) {
            #pragma unroll
            for (int msk = 1; msk <= 8; msk <<= 1) mr[r] = fmaxf(mr[r], __shfl_xor(mr[r], msk));
        }
        float lr[4] = {0.f, 0.f, 0.f, 0.f};
        #pragma unroll
        for (int j = 0; j < 13; ++j)
            #pragma unroll
            for (int r = 0; r < 4; ++r) { float e = __expf(sc[j][r] - mr[r]); sc[j][r] = e; lr[r] += e; }
        #pragma unroll
        for (int r = 0; r < 4; ++r) {
            #pragma unroll
            for (int msk = 1; msk <= 8; msk <<= 1) lr[r] += __shfl_xor(lr[r], msk);
            lr[r] = 1.f / lr[r];
        }
        #pragma unroll
        for (int j = 0; j < 13; ++j) {
            int col = j * 16 + c;
            #pragma unroll
            for (int r = 0; r < 4; ++r) {
                int q = g * 4 + r;
                Pl[wid][q * 256 + (col ^ ((q & 7) << 3))] = f2b(sc[j][r] * lr[r]);
            }
        }
        asm volatile("s_waitcnt lgkmcnt(0)" ::: "memory");

        f32x4 av[4] = {};
        #pragma unroll
        for (int ks = 0; ks < 7; ++ks) {
            int kk = ks * 32 + g * 8;
            bf16x8 ap = *(const bf16x8*)&Pl[wid][c * 256 + (kk ^ ((c & 7) << 3))];
            #pragma unroll
            for (int jd = 0; jd < 4; ++jd) {
                int dr = jd * 16 + c;
                bf16x8 bv = *(const bf16x8*)&VT[dr * 256 + (kk ^ ((dr & 7) << 3))];
                av[jd] = __builtin_amdgcn_mfma_f32_16x16x32_bf16(ap, bv, av[jd], 0, 0, 0);
            }
        }
        #pragma unroll
        for (int jd = 0; jd < 4; ++jd) {
            #pragma unroll
            for (int r = 0; r < 4; ++r) {
                int q = q0 + g * 4 + r;
                if (q < 197)
                    o[((size_t)b * 197 + q) * 384 + hh * 64 + jd * 16 + c] = f2b(av[jd][r]);
            }
        }
    }
}

// ---------------------------------------------------------------- cls output (fp32)
__global__ void k_clsout(const float* __restrict__ tokn, float* __restrict__ out) {
    int idx = blockIdx.x * 256 + threadIdx.x;   // < 6144
    int b = idx / 384, d = idx % 384;
    out[idx] = tokn[(size_t)b * 197 * 384 + d];
}

// ---------------------------------------------------------------- feature normalize -> bf16 (B*196, 384)
__global__ __launch_bounds__(256) void k_fn(const float* __restrict__ tokn, __hip_bfloat16* __restrict__ fn) {
    int wid = threadIdx.x >> 6, lane = threadIdx.x & 63;
    int row = blockIdx.x * 4 + wid;   // < 3136
    int b = row / 196, n = row % 196;
    const float* xr = tokn + ((size_t)b * 197 + 1 + n) * 384;
    const float* cr = tokn + (size_t)b * 197 * 384;
    float v[6], ss = 0.f;
    #pragma unroll
    for (int i = 0; i < 6; ++i) {
        int d = lane + 64 * i;
        float t = xr[d] - cr[d];
        v[i] = t; ss += t * t;
    }
    #pragma unroll
    for (int m = 32; m > 0; m >>= 1) ss += __shfl_xor(ss, m);
    float inv = 1.f / fmaxf(sqrtf(ss), 1e-12f);
    #pragma unroll
    for (int i = 0; i < 6; ++i) fn[(size_t)row * 384 + lane + 64 * i] = __float2bfloat16(v[i] * inv);
}

// ---------------------------------------------------------------- proto normalize + transpose -> bf16 (8000, 384)
__global__ __launch_bounds__(256) void k_pn(const float* __restrict__ proto, __hip_bfloat16* __restrict__ pn) {
    int p = blockIdx.x;
    int k = threadIdx.x >> 6, lane = threadIdx.x & 63;
    float v[6], ss = 0.f;
    #pragma unroll
    for (int i = 0; i < 6; ++i) {
        int d = lane + 64 * i;
        float t = proto[((size_t)p * 384 + d) * 4 + k];
        v[i] = t; ss += t * t;
    }
    #pragma unroll
    for (int m = 32; m > 0; m >>= 1) ss += __shfl_xor(ss, m);
    float inv = 1.f / fmaxf(sqrtf(ss), 1e-12f);
    #pragma unroll
    for (int i = 0; i < 6; ++i) pn[((size_t)p * 4 + k) * 384 + lane + 64 * i] = __float2bfloat16(v[i] * inv);
}

// ---------------------------------------------------------------- top4 helper
__device__ __forceinline__ void top4_insert(float v, float& t0, float& t1, float& t2, float& t3) {
    if (v > t3) {
        t3 = v;
        if (t3 > t2) { float t = t2; t2 = t3; t3 = t; }
        if (t2 > t1) { float t = t1; t1 = t2; t2 = t; }
        if (t1 > t0) { float t = t0; t0 = t1; t1 = t; }
    }
}

// ---------------------------------------------------------------- dist: bf16 MFMA GEMM + fused top-4 + score
// Staging via global_load_lds with pre-swizzled global source (no reg staging -> no spills).
__global__ __launch_bounds__(256) void k_dist_mfma(
    const __hip_bfloat16* __restrict__ fnb, const __hip_bfloat16* __restrict__ pnb,
    const float* __restrict__ psel, float* __restrict__ out)
{
    __shared__ u16 Ap[128 * 64];
    __shared__ u16 Bf[208 * 64];
    const u16* fn = (const u16*)fnb;
    const u16* pn = (const u16*)pnb;
    const int b = blockIdx.x;
    const int pb = blockIdx.y;
    const int tid = threadIdx.x, wid = tid >> 6, lane = tid & 63;
    const int srow = tid >> 3;
    const int selem = (tid & 7) << 3;

    f32x4 acc[2][13] = {};

    for (int kt = 0; kt < 384; kt += 64) {
        __syncthreads();
        #pragma unroll
        for (int g = 0; g < 4; ++g) {
            int r = g * 32 + srow;
            int gr = pb * 128 + r; if (gr > 7999) gr = 7999;
            async_copy16(&Ap[r * 64 + selem],
                         pn + (size_t)gr * 384 + kt + (selem ^ ((r & 7) << 3)));
        }
        #pragma unroll
        for (int g = 0; g < 7; ++g) {
            int r = g * 32 + srow;
            if (r < 208) {   // wave-uniform (8-row granularity)
                int fr = r > 195 ? 195 : r;
                async_copy16(&Bf[r * 64 + selem],
                             fn + ((size_t)b * 196 + fr) * 384 + kt + (selem ^ ((r & 7) << 3)));
            }
        }
        __syncthreads();
        #pragma unroll
        for (int ks = 0; ks < 64; ks += 32) {
            const int kk = ks + ((lane >> 4) << 3);
            bf16x8 af[2];
            #pragma unroll
            for (int i = 0; i < 2; ++i) {
                int r = wid * 32 + i * 16 + (lane & 15);
                af[i] = *(const bf16x8*)&Ap[r * 64 + (kk ^ ((r & 7) << 3))];
            }
            #pragma unroll
            for (int j = 0; j < 13; ++j) {
                int r = j * 16 + (lane & 15);
                bf16x8 bj = *(const bf16x8*)&Bf[r * 64 + (kk ^ ((r & 7) << 3))];
                acc[0][j] = __builtin_amdgcn_mfma_f32_16x16x32_bf16(af[0], bj, acc[0][j], 0, 0, 0);
                acc[1][j] = __builtin_amdgcn_mfma_f32_16x16x32_bf16(af[1], bj, acc[1][j], 0, 0, 0);
            }
        }
    }
    const int cl = lane & 15;
    #pragma unroll
    for (int mi = 0; mi < 2; ++mi) {
        float t0 = -1e30f, t1 = -1e30f, t2 = -1e30f, t3 = -1e30f;
        #pragma unroll
        for (int j = 0; j < 13; ++j) {
            if (j * 16 + cl >= 196) continue;
            #pragma unroll
            for (int r = 0; r < 4; ++r) top4_insert(acc[mi][j][r], t0, t1, t2, t3);
        }
        #pragma unroll
        for (int m = 1; m <= 8; m <<= 1) {
            float u0 = __shfl_xor(t0, m), u1 = __shfl_xor(t1, m);
            float u2 = __shfl_xor(t2, m), u3 = __shfl_xor(t3, m);
            top4_insert(u0, t0, t1, t2, t3);
            top4_insert(u1, t0, t1, t2, t3);
            top4_insert(u2, t0, t1, t2, t3);
            top4_insert(u3, t0, t1, t2, t3);
        }
        if (cl == 0) {
            int proto = pb * 32 + wid * 8 + mi * 4 + (lane >> 4);
            if (proto < 2000) {
                float sl[4], fac = 1e-10f;
                #pragma unroll
                for (int i = 0; i < 4; ++i) {
                    sl[i] = 1.f / (1.f + expf(-psel[proto * 4 + i] * 100.f));
                    fac += sl[i];
                }
                float score = (t0 * sl[0] + t1 * sl[1] + t2 * sl[2] + t3 * sl[3]) * 4.f / fac;
                out[6144 + (size_t)b * 2000 + proto] = score;
            }
        }
    }
}

// ---------------------------------------------------------------- host launcher
extern "C" void kernel_launch(void* const* d_in, const int* in_sizes, int n_in,
                              void* d_out, int out_size, void* d_ws, size_t ws_size,
                              hipStream_t stream) {
    const float* x       = (const float*)d_in[0];
    const float* patch_w = (const float*)d_in[1];
    const float* patch_b = (const float*)d_in[2];
    const float* cls_tok = (const float*)d_in[3];
    const float* pos     = (const float*)d_in[4];
    const float* ln1_s   = (const float*)d_in[5];
    const float* ln1_b   = (const float*)d_in[6];
    const float* qkv_w   = (const float*)d_in[7];
    const float* qkv_b   = (const float*)d_in[8];
    const float* proj_w  = (const float*)d_in[9];
    const float* proj_b  = (const float*)d_in[10];
    const float* ln2_s   = (const float*)d_in[11];
    const float* ln2_b   = (const float*)d_in[12];
    const float* fc1_w   = (const float*)d_in[13];
    const float* fc1_b   = (const float*)d_in[14];
    const float* fc2_w   = (const float*)d_in[15];
    const float* fc2_b   = (const float*)d_in[16];
    const float* norm_s  = (const float*)d_in[17];
    const float* norm_b  = (const float*)d_in[18];
    const float* proto   = (const float*)d_in[19];
    const float* psel    = (const float*)d_in[20];
    float* out = (float*)d_out;
    char* w = (char*)d_ws;

    __hip_bfloat16* wPb  = (__hip_bfloat16*)(w);             // 589824
    __hip_bfloat16* wQ   = (__hip_bfloat16*)(w + 589824);    // 5308416
    __hip_bfloat16* wPr  = (__hip_bfloat16*)(w + 5898240);   // 1769472
    __hip_bfloat16* wF1  = (__hip_bfloat16*)(w + 7667712);   // 7077888
    __hip_bfloat16* wF2  = (__hip_bfloat16*)(w + 14745600);  // 7077888
    __hip_bfloat16* Acol = (__hip_bfloat16*)(w + 21823488);  // 4816896
    float*          ptmp = (float*)         (w + 26640384);  // 4816896
    float*          tok  = (float*)         (w + 31457280);  // 4841472
    __hip_bfloat16* hbf  = (__hip_bfloat16*)(w + 36298752);  // 2420736
    __hip_bfloat16* qkvb = (__hip_bfloat16*)(w + 38719488);  // 7262208
    __hip_bfloat16* aob  = (__hip_bfloat16*)(w + 53243904);  // 2420736
    __hip_bfloat16* hbig = (__hip_bfloat16*)(w + 55664640);  // 9682944
    float*          hf   = (float*)         (w + 65347584);  // 4841472
    __hip_bfloat16* fnb  = (__hip_bfloat16*)(w + 70189056);  // 2408448
    __hip_bfloat16* pnb  = (__hip_bfloat16*)(w + 72597504);  // 6144000

    k_cvt<<<1152, 256, 0, stream>>>(patch_w, wPb, 294912);
    k_wt<<<dim3(36, 12, 6), 256, 0, stream>>>(qkv_w, wQ, 384, 1152);
    k_wt<<<dim3(12, 12, 6), 256, 0, stream>>>(proj_w, wPr, 384, 384);
    k_wt<<<dim3(48, 12, 6), 256, 0, stream>>>(fc1_w, wF1, 384, 1536);
    k_wt<<<dim3(12, 48, 6), 256, 0, stream>>>(fc2_w, wF2, 1536, 384);

    k_im2col<<<9408, 256, 0, stream>>>(x, Acol);
    k_mfma_gemm64<0,0,0><<<dim3(6, 25), 256, 0, stream>>>(
        (const u16*)Acol, (const u16*)wPb, patch_b, nullptr, ptmp, nullptr, 3136, 384, 768);
    k_assemble<<<4728, 256, 0, stream>>>(ptmp, cls_tok, pos, tok);

    for (int l = 0; l < 6; ++l) {
        k_ln<__hip_bfloat16><<<788, 256, 0, stream>>>(tok, ln1_s + l * 384, ln1_b + l * 384, hbf, MROWS);
        k_mfma_gemm<0,0,1><<<dim3(9, 25), 256, 0, stream>>>(
            (const u16*)hbf, (const u16*)(wQ + (size_t)l * 1152 * 384), qkv_b + l * 1152,
            nullptr, nullptr, qkvb, MROWS, 1152, 384);
        k_attn_mfma<<<dim3(96, 2), 256, 0, stream>>>((const u16*)qkvb, (u16*)aob);
        k_mfma_gemm64<1,0,0><<<dim3(6, 25), 256, 0, stream>>>(
            (const u16*)aob, (const u16*)(wPr + (size_t)l * 384 * 384), proj_b + l * 384,
            tok, tok, nullptr, MROWS, 384, 384);
        k_ln<__hip_bfloat16><<<788, 256, 0, stream>>>(tok, ln2_s + l * 384, ln2_b + l * 384, hbf, MROWS);
        k_mfma_gemm<0,1,1><<<dim3(12, 25), 256, 0, stream>>>(
            (const u16*)hbf, (const u16*)(wF1 + (size_t)l * 1536 * 384), fc1_b + l * 1536,
            nullptr, nullptr, hbig, MROWS, 1536, 384);
        k_mfma_gemm64<1,0,0><<<dim3(6, 25), 256, 0, stream>>>(
            (const u16*)hbig, (const u16*)(wF2 + (size_t)l * 384 * 1536), fc2_b + l * 384,
            tok, tok, nullptr, MROWS, 384, 1536);
    }

    k_ln<float><<<788, 256, 0, stream>>>(tok, norm_s, norm_b, hf, MROWS);
    k_clsout<<<24, 256, 0, stream>>>(hf, out);
    k_fn<<<784, 256, 0, stream>>>(hf, fnb);
    k_pn<<<2000, 256, 0, stream>>>(proto, pnb);
    k_dist_mfma<<<dim3(16, 63), 256, 0, stream>>>(fnb, pnb, psel, out);
}

// Round 5
// 747.188 us; speedup vs baseline: 4.0022x; 1.0262x over previous
//
#include <hip/hip_runtime.h>
#include <hip/hip_bf16.h>
#include <math.h>

// ProtoViT forward: bf16-MFMA GEMMs (double-buffered T3-min pipeline) +
// MFMA attention + fp32 residual/LN path.
// B=16, D=384, DEPTH=6, H=6, HD=64, P=2000, NP=4, N=196, T=197.

#define MROWS 3152   // 16*197

typedef short bf16x8 __attribute__((ext_vector_type(8)));
typedef float f32x4 __attribute__((ext_vector_type(4)));
typedef unsigned short u16;

__device__ __forceinline__ void async_copy16(void* lds, const void* g) {
    __builtin_amdgcn_global_load_lds((const __attribute__((address_space(1))) unsigned int*)g,
                                     (__attribute__((address_space(3))) unsigned int*)lds,
                                     16, 0, 0);
}

__device__ __forceinline__ u16 f2b(float x) {
    __hip_bfloat16 h = __float2bfloat16(x);
    return *(u16*)&h;
}

// ---------------------------------------------------------------- fp32 -> bf16 elementwise
__global__ void k_cvt(const float* __restrict__ in, __hip_bfloat16* __restrict__ o, int n) {
    int i = blockIdx.x * 256 + threadIdx.x;
    if (i < n) o[i] = __float2bfloat16(in[i]);
}

// ---------------------------------------------------------------- weight transpose (K,N) f32 -> (N,K) bf16, per layer z
__global__ __launch_bounds__(256) void k_wt(const float* __restrict__ W, __hip_bfloat16* __restrict__ Wt,
                                            int K, int N) {
    __shared__ float t[32][33];
    const float* src = W + (size_t)blockIdx.z * K * N;
    __hip_bfloat16* dst = Wt + (size_t)blockIdx.z * K * N;
    int n0 = blockIdx.x * 32, k0 = blockIdx.y * 32;
    int tx = threadIdx.x & 31, ty = threadIdx.x >> 5;   // 32 x 8
    #pragma unroll
    for (int i = 0; i < 4; ++i) t[ty + i * 8][tx] = src[(size_t)(k0 + ty + i * 8) * N + n0 + tx];
    __syncthreads();
    #pragma unroll
    for (int i = 0; i < 4; ++i)
        dst[(size_t)(n0 + ty + i * 8) * K + k0 + tx] = __float2bfloat16(t[tx][ty + i * 8]);
}

// ---------------------------------------------------------------- im2col -> bf16 (B*196, 768)
__global__ void k_im2col(const float* __restrict__ x, __hip_bfloat16* __restrict__ Acol) {
    int idx = blockIdx.x * 256 + threadIdx.x;    // < 3136*768
    int k = idx % 768;
    int m = idx / 768;
    int b = m / 196, n = m % 196;
    int c = k >> 8, rem = k & 255, i = rem >> 4, j = rem & 15;
    int py = n / 14, px = n % 14;
    Acol[idx] = __float2bfloat16(x[((b * 3 + c) * 224 + py * 16 + i) * 224 + px * 16 + j]);
}

// ---------------------------------------------------------------- bf16 MFMA GEMM, 128x128 tile, double-buffered
template<int RES, int GELU, int BF16OUT>
__global__ __launch_bounds__(256) void k_mfma_gemm(
    const u16* __restrict__ A, const u16* __restrict__ Bt,
    const float* __restrict__ bias, const float* __restrict__ res,
    float* __restrict__ Cf, __hip_bfloat16* __restrict__ Cb,
    int M, int N, int K)
{
    __shared__ u16 As[2][128 * 64];
    __shared__ u16 Bs[2][128 * 64];
    const int tid = threadIdx.x;
    const int wid = tid >> 6, lane = tid & 63;
    const int m0 = blockIdx.y * 128, n0 = blockIdx.x * 128;
    const int srow = tid >> 3;          // 0..31
    const int selem = (tid & 7) << 3;   // 0..56
    const int wm = (wid >> 1) * 64, wn = (wid & 1) * 64;

    f32x4 acc[4][4] = {};

    auto stage = [&](int buf, int kb) {
        #pragma unroll
        for (int g = 0; g < 4; ++g) {
            int r = g * 32 + srow;
            int gr = m0 + r; if (gr > M - 1) gr = M - 1;
            async_copy16(&As[buf][r * 64 + selem], A + (size_t)gr * K + kb + selem);
            async_copy16(&Bs[buf][r * 64 + selem], Bt + (size_t)(n0 + r) * K + kb + selem);
        }
    };

    const int nk = K >> 6;
    stage(0, 0);
    __syncthreads();
    for (int t = 0; t < nk; ++t) {
        const int cur = t & 1;
        if (t + 1 < nk) stage(cur ^ 1, (t + 1) << 6);
        #pragma unroll
        for (int ks = 0; ks < 64; ks += 32) {
            const int kk = ks + ((lane >> 4) << 3);
            bf16x8 af[4], bfr[4];
            #pragma unroll
            for (int i = 0; i < 4; ++i)
                af[i] = *(const bf16x8*)&As[cur][(wm + i * 16 + (lane & 15)) * 64 + kk];
            #pragma unroll
            for (int j = 0; j < 4; ++j)
                bfr[j] = *(const bf16x8*)&Bs[cur][(wn + j * 16 + (lane & 15)) * 64 + kk];
            #pragma unroll
            for (int i = 0; i < 4; ++i)
                #pragma unroll
                for (int j = 0; j < 4; ++j)
                    acc[i][j] = __builtin_amdgcn_mfma_f32_16x16x32_bf16(af[i], bfr[j], acc[i][j], 0, 0, 0);
        }
        __syncthreads();
    }
    const int cl = lane & 15, rg = (lane >> 4) << 2;
    #pragma unroll
    for (int i = 0; i < 4; ++i) {
        #pragma unroll
        for (int j = 0; j < 4; ++j) {
            const int col = n0 + wn + j * 16 + cl;
            const float bv = bias[col];
            #pragma unroll
            for (int r = 0; r < 4; ++r) {
                const int row = m0 + wm + i * 16 + rg + r;
                if (row >= M) continue;
                float v = acc[i][j][r] + bv;
                if (RES) v += res[(size_t)row * N + col];
                if (GELU) v = 0.5f * v * (1.0f + erff(v * 0.70710678118f));
                if (BF16OUT) Cb[(size_t)row * N + col] = __float2bfloat16(v);
                else         Cf[(size_t)row * N + col] = v;
            }
        }
    }
}

// ---------------------------------------------------------------- bf16 MFMA GEMM, 128x64 tile, double-buffered
template<int RES, int GELU, int BF16OUT>
__global__ __launch_bounds__(256) void k_mfma_gemm64(
    const u16* __restrict__ A, const u16* __restrict__ Bt,
    const float* __restrict__ bias, const float* __restrict__ res,
    float* __restrict__ Cf, __hip_bfloat16* __restrict__ Cb,
    int M, int N, int K)
{
    __shared__ u16 As[2][128 * 64];
    __shared__ u16 Bs[2][64 * 64];
    const int tid = threadIdx.x;
    const int wid = tid >> 6, lane = tid & 63;
    const int m0 = blockIdx.y * 128, n0 = blockIdx.x * 64;
    const int srow = tid >> 3;
    const int selem = (tid & 7) << 3;
    const int wm = wid * 32;

    f32x4 acc[2][4] = {};

    auto stage = [&](int buf, int kb) {
        #pragma unroll
        for (int g = 0; g < 4; ++g) {
            int r = g * 32 + srow;
            int gr = m0 + r; if (gr > M - 1) gr = M - 1;
            async_copy16(&As[buf][r * 64 + selem], A + (size_t)gr * K + kb + selem);
        }
        #pragma unroll
        for (int g = 0; g < 2; ++g) {
            int r = g * 32 + srow;
            async_copy16(&Bs[buf][r * 64 + selem], Bt + (size_t)(n0 + r) * K + kb + selem);
        }
    };

    const int nk = K >> 6;
    stage(0, 0);
    __syncthreads();
    for (int t = 0; t < nk; ++t) {
        const int cur = t & 1;
        if (t + 1 < nk) stage(cur ^ 1, (t + 1) << 6);
        #pragma unroll
        for (int ks = 0; ks < 64; ks += 32) {
            const int kk = ks + ((lane >> 4) << 3);
            bf16x8 af[2], bfr[4];
            #pragma unroll
            for (int i = 0; i < 2; ++i)
                af[i] = *(const bf16x8*)&As[cur][(wm + i * 16 + (lane & 15)) * 64 + kk];
            #pragma unroll
            for (int j = 0; j < 4; ++j)
                bfr[j] = *(const bf16x8*)&Bs[cur][(j * 16 + (lane & 15)) * 64 + kk];
            #pragma unroll
            for (int i = 0; i < 2; ++i)
                #pragma unroll
                for (int j = 0; j < 4; ++j)
                    acc[i][j] = __builtin_amdgcn_mfma_f32_16x16x32_bf16(af[i], bfr[j], acc[i][j], 0, 0, 0);
        }
        __syncthreads();
    }
    const int cl = lane & 15, rg = (lane >> 4) << 2;
    #pragma unroll
    for (int i = 0; i < 2; ++i) {
        #pragma unroll
        for (int j = 0; j < 4; ++j) {
            const int col = n0 + j * 16 + cl;
            const float bv = bias[col];
            #pragma unroll
            for (int r = 0; r < 4; ++r) {
                const int row = m0 + wm + i * 16 + rg + r;
                if (row >= M) continue;
                float v = acc[i][j][r] + bv;
                if (RES) v += res[(size_t)row * N + col];
                if (GELU) v = 0.5f * v * (1.0f + erff(v * 0.70710678118f));
                if (BF16OUT) Cb[(size_t)row * N + col] = __float2bfloat16(v);
                else         Cf[(size_t)row * N + col] = v;
            }
        }
    }
}

// ---------------------------------------------------------------- assemble tokens: cls + patches + pos (fp32)
__global__ void k_assemble(const float* __restrict__ ptmp, const float* __restrict__ cls_tok,
                           const float* __restrict__ pos, float* __restrict__ tok) {
    int idx = blockIdx.x * 256 + threadIdx.x;   // < 16*197*384
    int d = idx % 384;
    int t = (idx / 384) % 197;
    int b = idx / (384 * 197);
    float v = (t == 0) ? cls_tok[d] : ptmp[((size_t)b * 196 + t - 1) * 384 + d];
    tok[idx] = v + pos[t * 384 + d];
}

// ---------------------------------------------------------------- layernorm (fp32 compute), OT output
template<typename OT>
__global__ __launch_bounds__(256) void k_ln(const float* __restrict__ X, const float* __restrict__ s,
                                            const float* __restrict__ bb, OT* __restrict__ Y, int rows) {
    int wid = threadIdx.x >> 6, lane = threadIdx.x & 63;
    int row = blockIdx.x * 4 + wid;
    if (row >= rows) return;
    const float* x = X + (size_t)row * 384;
    float v[6], sum = 0.f, sq = 0.f;
    #pragma unroll
    for (int i = 0; i < 6; ++i) { float t = x[lane + 64 * i]; v[i] = t; sum += t; sq += t * t; }
    #pragma unroll
    for (int m = 32; m > 0; m >>= 1) { sum += __shfl_xor(sum, m); sq += __shfl_xor(sq, m); }
    float mean = sum * (1.f / 384.f);
    float var  = sq * (1.f / 384.f) - mean * mean;
    float rstd = rsqrtf(var + 1e-6f);
    OT* y = Y + (size_t)row * 384;
    #pragma unroll
    for (int i = 0; i < 6; ++i) {
        int d = lane + 64 * i;
        float o = (v[i] - mean) * rstd * s[d] + bb[d];
        y[d] = (OT)o;
    }
}

// ---------------------------------------------------------------- MFMA attention
__global__ __launch_bounds__(256) void k_attn_mfma(const u16* __restrict__ qkv, u16* __restrict__ o) {
    __shared__ u16 Ks[208 * 64];       // K rows, XOR-swizzled 16B chunks
    __shared__ u16 VT[64 * 256];       // V^T rows (d, k), swizzled, tail-zeroed
    __shared__ u16 Pl[4][16 * 256];    // per-wave P tile (q_local, k), swizzled
    const int bh = blockIdx.x;
    const int b = bh / 6, hh = bh % 6;
    const u16* base = qkv + (size_t)b * 197 * 1152 + hh * 64;
    const int tid = threadIdx.x, wid = tid >> 6, lane = tid & 63;

    for (int i = tid; i < 64 * 59; i += 256) {
        int d = i / 59, k = 197 + i % 59;
        VT[d * 256 + (k ^ ((d & 7) << 3))] = 0;
    }
    for (int i = tid; i < 64 * 48; i += 256) {
        int q = i / 48, k = 208 + i % 48;
        Pl[q >> 4][(q & 15) * 256 + (k ^ ((q & 7) << 3))] = 0;
    }
    for (int i = tid; i < 197 * 8; i += 256) {
        int r = i >> 3, cc = (i & 7) << 3;
        uint4 v = *(const uint4*)(base + (size_t)r * 1152 + 384 + cc);
        *(uint4*)&Ks[r * 64 + (cc ^ ((r & 7) << 3))] = v;
    }
    for (int i = tid; i < 197 * 8; i += 256) {
        int r = i >> 3, d0 = (i & 7) << 3;
        uint4 v = *(const uint4*)(base + (size_t)r * 1152 + 768 + d0);
        const u16* pv = (const u16*)&v;
        #pragma unroll
        for (int j = 0; j < 8; ++j) {
            int d = d0 + j;
            VT[d * 256 + (r ^ ((d & 7) << 3))] = pv[j];
        }
    }
    __syncthreads();

    const int g = lane >> 4, c = lane & 15;
    const int t0 = blockIdx.y * 7;
    const int nt = blockIdx.y ? 6 : 7;
    for (int t = wid; t < nt; t += 4) {
        const int qt = t0 + t;
        const int q0 = qt * 16;
        int qrow = q0 + c; if (qrow > 196) qrow = 196;
        bf16x8 aq[2];
        aq[0] = *(const bf16x8*)(base + (size_t)qrow * 1152 + g * 8);
        aq[1] = *(const bf16x8*)(base + (size_t)qrow * 1152 + 32 + g * 8);

        f32x4 acc[13] = {};
        #pragma unroll
        for (int j = 0; j < 13; ++j) {
            int kr = j * 16 + c;
            bf16x8 b0 = *(const bf16x8*)&Ks[kr * 64 + ((g * 8) ^ ((kr & 7) << 3))];
            bf16x8 b1 = *(const bf16x8*)&Ks[kr * 64 + ((32 + g * 8) ^ ((kr & 7) << 3))];
            acc[j] = __builtin_amdgcn_mfma_f32_16x16x32_bf16(aq[0], b0, acc[j], 0, 0, 0);
            acc[j] = __builtin_amdgcn_mfma_f32_16x16x32_bf16(aq[1], b1, acc[j], 0, 0, 0);
        }

        float sc[13][4];
        float mr[4] = {-1e30f, -1e30f, -1e30f, -1e30f};
        #pragma unroll
        for (int j = 0; j < 13; ++j) {
            bool valid = (j * 16 + c) < 197;
            #pragma unroll
            for (int r = 0; r < 4; ++r) {
                float v = valid ? acc[j][r] * 0.125f : -1e30f;
                sc[j][r] = v;
                mr[r] = fmaxf(mr[r], v);
            }
        }
        #pragma unroll
        for (int r = 0; r < 4; ++r) {
            #pragma unroll
            for (int msk = 1; msk <= 8; msk <<= 1) mr[r] = fmaxf(mr[r], __shfl_xor(mr[r], msk));
        }
        float lr[4] = {0.f, 0.f, 0.f, 0.f};
        #pragma unroll
        for (int j = 0; j < 13; ++j)
            #pragma unroll
            for (int r = 0; r < 4; ++r) { float e = __expf(sc[j][r] - mr[r]); sc[j][r] = e; lr[r] += e; }
        #pragma unroll
        for (int r = 0; r < 4; ++r) {
            #pragma unroll
            for (int msk = 1; msk <= 8; msk <<= 1) lr[r] += __shfl_xor(lr[r], msk);
            lr[r] = 1.f / lr[r];
        }
        #pragma unroll
        for (int j = 0; j < 13; ++j) {
            int col = j * 16 + c;
            #pragma unroll
            for (int r = 0; r < 4; ++r) {
                int q = g * 4 + r;
                Pl[wid][q * 256 + (col ^ ((q & 7) << 3))] = f2b(sc[j][r] * lr[r]);
            }
        }
        asm volatile("s_waitcnt lgkmcnt(0)" ::: "memory");

        f32x4 av[4] = {};
        #pragma unroll
        for (int ks = 0; ks < 7; ++ks) {
            int kk = ks * 32 + g * 8;
            bf16x8 ap = *(const bf16x8*)&Pl[wid][c * 256 + (kk ^ ((c & 7) << 3))];
            #pragma unroll
            for (int jd = 0; jd < 4; ++jd) {
                int dr = jd * 16 + c;
                bf16x8 bv = *(const bf16x8*)&VT[dr * 256 + (kk ^ ((dr & 7) << 3))];
                av[jd] = __builtin_amdgcn_mfma_f32_16x16x32_bf16(ap, bv, av[jd], 0, 0, 0);
            }
        }
        #pragma unroll
        for (int jd = 0; jd < 4; ++jd) {
            #pragma unroll
            for (int r = 0; r < 4; ++r) {
                int q = q0 + g * 4 + r;
                if (q < 197)
                    o[((size_t)b * 197 + q) * 384 + hh * 64 + jd * 16 + c] = f2b(av[jd][r]);
            }
        }
    }
}

// ---------------------------------------------------------------- feature normalize -> bf16 + cls copy-out
__global__ __launch_bounds__(256) void k_fn(const float* __restrict__ tokn, __hip_bfloat16* __restrict__ fn,
                                            float* __restrict__ out) {
    int wid = threadIdx.x >> 6, lane = threadIdx.x & 63;
    int row = blockIdx.x * 4 + wid;   // < 3136
    int b = row / 196, n = row % 196;
    const float* xr = tokn + ((size_t)b * 197 + 1 + n) * 384;
    const float* cr = tokn + (size_t)b * 197 * 384;
    float v[6], ss = 0.f;
    #pragma unroll
    for (int i = 0; i < 6; ++i) {
        int d = lane + 64 * i;
        float t = xr[d] - cr[d];
        v[i] = t; ss += t * t;
    }
    #pragma unroll
    for (int m = 32; m > 0; m >>= 1) ss += __shfl_xor(ss, m);
    float inv = 1.f / fmaxf(sqrtf(ss), 1e-12f);
    #pragma unroll
    for (int i = 0; i < 6; ++i) fn[(size_t)row * 384 + lane + 64 * i] = __float2bfloat16(v[i] * inv);
    // cls output: first 24 blocks cover 16*384 = 6144 elems
    int idx = blockIdx.x * 256 + threadIdx.x;
    if (idx < 6144) out[idx] = tokn[(size_t)(idx / 384) * 197 * 384 + idx % 384];
}

// ---------------------------------------------------------------- proto normalize + transpose -> bf16 (8000, 384)
__global__ __launch_bounds__(256) void k_pn(const float* __restrict__ proto, __hip_bfloat16* __restrict__ pn) {
    int p = blockIdx.x;
    int k = threadIdx.x >> 6, lane = threadIdx.x & 63;
    float v[6], ss = 0.f;
    #pragma unroll
    for (int i = 0; i < 6; ++i) {
        int d = lane + 64 * i;
        float t = proto[((size_t)p * 384 + d) * 4 + k];
        v[i] = t; ss += t * t;
    }
    #pragma unroll
    for (int m = 32; m > 0; m >>= 1) ss += __shfl_xor(ss, m);
    float inv = 1.f / fmaxf(sqrtf(ss), 1e-12f);
    #pragma unroll
    for (int i = 0; i < 6; ++i) pn[((size_t)p * 4 + k) * 384 + lane + 64 * i] = __float2bfloat16(v[i] * inv);
}

// ---------------------------------------------------------------- top4 helper
__device__ __forceinline__ void top4_insert(float v, float& t0, float& t1, float& t2, float& t3) {
    if (v > t3) {
        t3 = v;
        if (t3 > t2) { float t = t2; t2 = t3; t3 = t; }
        if (t2 > t1) { float t = t1; t1 = t2; t2 = t; }
        if (t1 > t0) { float t = t0; t0 = t1; t1 = t; }
    }
}

// ---------------------------------------------------------------- dist: bf16 MFMA GEMM + fused top-4 + score
// BK=32, double-buffered global_load_lds staging with pre-swizzled source.
__global__ __launch_bounds__(256) void k_dist_mfma(
    const __hip_bfloat16* __restrict__ fnb, const __hip_bfloat16* __restrict__ pnb,
    const float* __restrict__ psel, float* __restrict__ out)
{
    __shared__ u16 Ap[2][128 * 32];
    __shared__ u16 Bf[2][208 * 32];
    const u16* fn = (const u16*)fnb;
    const u16* pn = (const u16*)pnb;
    const int b = blockIdx.x;
    const int pb = blockIdx.y;
    const int tid = threadIdx.x, wid = tid >> 6, lane = tid & 63;

    f32x4 acc[2][13] = {};

    auto stage = [&](int buf, int kb) {
        #pragma unroll
        for (int rep = 0; rep < 2; ++rep) {            // A: 512 chunks
            int i = rep * 256 + tid;
            int row = i >> 2, sub = i & 3;
            int gr = pb * 128 + row; if (gr > 7999) gr = 7999;
            int scol = kb + ((sub ^ (row & 3)) << 3);
            async_copy16(&Ap[buf][row * 32 + (sub << 3)], pn + (size_t)gr * 384 + scol);
        }
        #pragma unroll
        for (int rep = 0; rep < 4; ++rep) {            // B: 832 chunks
            int i = rep * 256 + tid;
            if (i < 832) {
                int row = i >> 2, sub = i & 3;
                int fr = row > 195 ? 195 : row;
                int scol = kb + ((sub ^ (row & 3)) << 3);
                async_copy16(&Bf[buf][row * 32 + (sub << 3)], fn + ((size_t)b * 196 + fr) * 384 + scol);
            }
        }
    };

    stage(0, 0);
    __syncthreads();
    const int cl = lane & 15, c0 = lane >> 4;
    for (int t = 0; t < 12; ++t) {
        const int cur = t & 1;
        if (t + 1 < 12) stage(cur ^ 1, (t + 1) << 5);
        bf16x8 af[2];
        #pragma unroll
        for (int i = 0; i < 2; ++i) {
            int r = wid * 32 + i * 16 + cl;
            af[i] = *(const bf16x8*)&Ap[cur][r * 32 + ((c0 ^ (r & 3)) << 3)];
        }
        #pragma unroll
        for (int j = 0; j < 13; ++j) {
            int r = j * 16 + cl;
            bf16x8 bj = *(const bf16x8*)&Bf[cur][r * 32 + ((c0 ^ (r & 3)) << 3)];
            acc[0][j] = __builtin_amdgcn_mfma_f32_16x16x32_bf16(af[0], bj, acc[0][j], 0, 0, 0);
            acc[1][j] = __builtin_amdgcn_mfma_f32_16x16x32_bf16(af[1], bj, acc[1][j], 0, 0, 0);
        }
        __syncthreads();
    }
    #pragma unroll
    for (int mi = 0; mi < 2; ++mi) {
        float t0 = -1e30f, t1 = -1e30f, t2 = -1e30f, t3 = -1e30f;
        #pragma unroll
        for (int j = 0; j < 13; ++j) {
            if (j * 16 + cl >= 196) continue;
            #pragma unroll
            for (int r = 0; r < 4; ++r) top4_insert(acc[mi][j][r], t0, t1, t2, t3);
        }
        #pragma unroll
        for (int m = 1; m <= 8; m <<= 1) {
            float u0 = __shfl_xor(t0, m), u1 = __shfl_xor(t1, m);
            float u2 = __shfl_xor(t2, m), u3 = __shfl_xor(t3, m);
            top4_insert(u0, t0, t1, t2, t3);
            top4_insert(u1, t0, t1, t2, t3);
            top4_insert(u2, t0, t1, t2, t3);
            top4_insert(u3, t0, t1, t2, t3);
        }
        if (cl == 0) {
            int proto = pb * 32 + wid * 8 + mi * 4 + (lane >> 4);
            if (proto < 2000) {
                float sl[4], fac = 1e-10f;
                #pragma unroll
                for (int i = 0; i < 4; ++i) {
                    sl[i] = 1.f / (1.f + expf(-psel[proto * 4 + i] * 100.f));
                    fac += sl[i];
                }
                float score = (t0 * sl[0] + t1 * sl[1] + t2 * sl[2] + t3 * sl[3]) * 4.f / fac;
                out[6144 + (size_t)b * 2000 + proto] = score;
            }
        }
    }
}

// ---------------------------------------------------------------- host launcher
extern "C" void kernel_launch(void* const* d_in, const int* in_sizes, int n_in,
                              void* d_out, int out_size, void* d_ws, size_t ws_size,
                              hipStream_t stream) {
    const float* x       = (const float*)d_in[0];
    const float* patch_w = (const float*)d_in[1];
    const float* patch_b = (const float*)d_in[2];
    const float* cls_tok = (const float*)d_in[3];
    const float* pos     = (const float*)d_in[4];
    const float* ln1_s   = (const float*)d_in[5];
    const float* ln1_b   = (const float*)d_in[6];
    const float* qkv_w   = (const float*)d_in[7];
    const float* qkv_b   = (const float*)d_in[8];
    const float* proj_w  = (const float*)d_in[9];
    const float* proj_b  = (const float*)d_in[10];
    const float* ln2_s   = (const float*)d_in[11];
    const float* ln2_b   = (const float*)d_in[12];
    const float* fc1_w   = (const float*)d_in[13];
    const float* fc1_b   = (const float*)d_in[14];
    const float* fc2_w   = (const float*)d_in[15];
    const float* fc2_b   = (const float*)d_in[16];
    const float* norm_s  = (const float*)d_in[17];
    const float* norm_b  = (const float*)d_in[18];
    const float* proto   = (const float*)d_in[19];
    const float* psel    = (const float*)d_in[20];
    float* out = (float*)d_out;
    char* w = (char*)d_ws;

    __hip_bfloat16* wPb  = (__hip_bfloat16*)(w);             // 589824
    __hip_bfloat16* wQ   = (__hip_bfloat16*)(w + 589824);    // 5308416
    __hip_bfloat16* wPr  = (__hip_bfloat16*)(w + 5898240);   // 1769472
    __hip_bfloat16* wF1  = (__hip_bfloat16*)(w + 7667712);   // 7077888
    __hip_bfloat16* wF2  = (__hip_bfloat16*)(w + 14745600);  // 7077888
    __hip_bfloat16* Acol = (__hip_bfloat16*)(w + 21823488);  // 4816896
    float*          ptmp = (float*)         (w + 26640384);  // 4816896
    float*          tok  = (float*)         (w + 31457280);  // 4841472
    __hip_bfloat16* hbf  = (__hip_bfloat16*)(w + 36298752);  // 2420736
    __hip_bfloat16* qkvb = (__hip_bfloat16*)(w + 38719488);  // 7262208
    __hip_bfloat16* aob  = (__hip_bfloat16*)(w + 53243904);  // 2420736
    __hip_bfloat16* hbig = (__hip_bfloat16*)(w + 55664640);  // 9682944
    float*          hf   = (float*)         (w + 65347584);  // 4841472
    __hip_bfloat16* fnb  = (__hip_bfloat16*)(w + 70189056);  // 2408448
    __hip_bfloat16* pnb  = (__hip_bfloat16*)(w + 72597504);  // 6144000

    k_cvt<<<1152, 256, 0, stream>>>(patch_w, wPb, 294912);
    k_wt<<<dim3(36, 12, 6), 256, 0, stream>>>(qkv_w, wQ, 384, 1152);
    k_wt<<<dim3(12, 12, 6), 256, 0, stream>>>(proj_w, wPr, 384, 384);
    k_wt<<<dim3(48, 12, 6), 256, 0, stream>>>(fc1_w, wF1, 384, 1536);
    k_wt<<<dim3(12, 48, 6), 256, 0, stream>>>(fc2_w, wF2, 1536, 384);

    k_im2col<<<9408, 256, 0, stream>>>(x, Acol);
    k_mfma_gemm64<0,0,0><<<dim3(6, 25), 256, 0, stream>>>(
        (const u16*)Acol, (const u16*)wPb, patch_b, nullptr, ptmp, nullptr, 3136, 384, 768);
    k_assemble<<<4728, 256, 0, stream>>>(ptmp, cls_tok, pos, tok);

    for (int l = 0; l < 6; ++l) {
        k_ln<__hip_bfloat16><<<788, 256, 0, stream>>>(tok, ln1_s + l * 384, ln1_b + l * 384, hbf, MROWS);
        k_mfma_gemm<0,0,1><<<dim3(9, 25), 256, 0, stream>>>(
            (const u16*)hbf, (const u16*)(wQ + (size_t)l * 1152 * 384), qkv_b + l * 1152,
            nullptr, nullptr, qkvb, MROWS, 1152, 384);
        k_attn_mfma<<<dim3(96, 2), 256, 0, stream>>>((const u16*)qkvb, (u16*)aob);
        k_mfma_gemm64<1,0,0><<<dim3(6, 25), 256, 0, stream>>>(
            (const u16*)aob, (const u16*)(wPr + (size_t)l * 384 * 384), proj_b + l * 384,
            tok, tok, nullptr, MROWS, 384, 384);
        k_ln<__hip_bfloat16><<<788, 256, 0, stream>>>(tok, ln2_s + l * 384, ln2_b + l * 384, hbf, MROWS);
        k_mfma_gemm<0,1,1><<<dim3(12, 25), 256, 0, stream>>>(
            (const u16*)hbf, (const u16*)(wF1 + (size_t)l * 1536 * 384), fc1_b + l * 1536,
            nullptr, nullptr, hbig, MROWS, 1536, 384);
        k_mfma_gemm64<1,0,0><<<dim3(6, 25), 256, 0, stream>>>(
            (const u16*)hbig, (const u16*)(wF2 + (size_t)l * 384 * 1536), fc2_b + l * 384,
            tok, tok, nullptr, MROWS, 384, 1536);
    }

    k_ln<float><<<788, 256, 0, stream>>>(tok, norm_s, norm_b, hf, MROWS);
    k_fn<<<784, 256, 0, stream>>>(hf, fnb, out);
    k_pn<<<2000, 256, 0, stream>>>(proto, pnb);
    k_dist_mfma<<<dim3(16, 63), 256, 0, stream>>>(fnb, pnb, psel, out);
}

// Round 6
// 685.587 us; speedup vs baseline: 4.3618x; 1.0899x over previous
//
#include <hip/hip_runtime.h>
#include <hip/hip_bf16.h>
#include <math.h>

// ProtoViT forward: bf16-MFMA GEMMs (double-buffered, both-sides LDS swizzle) +
// MFMA attention + fp32 residual/LN path.
// B=16, D=384, DEPTH=6, H=6, HD=64, P=2000, NP=4, N=196, T=197.

#define MROWS 3152   // 16*197

typedef short bf16x8 __attribute__((ext_vector_type(8)));
typedef float f32x4 __attribute__((ext_vector_type(4)));
typedef unsigned short u16;

__device__ __forceinline__ void async_copy16(void* lds, const void* g) {
    __builtin_amdgcn_global_load_lds((const __attribute__((address_space(1))) unsigned int*)g,
                                     (__attribute__((address_space(3))) unsigned int*)lds,
                                     16, 0, 0);
}

__device__ __forceinline__ u16 f2b(float x) {
    __hip_bfloat16 h = __float2bfloat16(x);
    return *(u16*)&h;
}

// ---------------------------------------------------------------- fp32 -> bf16 elementwise
__global__ void k_cvt(const float* __restrict__ in, __hip_bfloat16* __restrict__ o, int n) {
    int i = blockIdx.x * 256 + threadIdx.x;
    if (i < n) o[i] = __float2bfloat16(in[i]);
}

// ---------------------------------------------------------------- weight transpose (K,N) f32 -> (N,K) bf16, per layer z
__global__ __launch_bounds__(256) void k_wt(const float* __restrict__ W, __hip_bfloat16* __restrict__ Wt,
                                            int K, int N) {
    __shared__ float t[32][33];
    const float* src = W + (size_t)blockIdx.z * K * N;
    __hip_bfloat16* dst = Wt + (size_t)blockIdx.z * K * N;
    int n0 = blockIdx.x * 32, k0 = blockIdx.y * 32;
    int tx = threadIdx.x & 31, ty = threadIdx.x >> 5;   // 32 x 8
    #pragma unroll
    for (int i = 0; i < 4; ++i) t[ty + i * 8][tx] = src[(size_t)(k0 + ty + i * 8) * N + n0 + tx];
    __syncthreads();
    #pragma unroll
    for (int i = 0; i < 4; ++i)
        dst[(size_t)(n0 + ty + i * 8) * K + k0 + tx] = __float2bfloat16(t[tx][ty + i * 8]);
}

// ---------------------------------------------------------------- im2col -> bf16 (B*196, 768)
__global__ void k_im2col(const float* __restrict__ x, __hip_bfloat16* __restrict__ Acol) {
    int idx = blockIdx.x * 256 + threadIdx.x;    // < 3136*768
    int k = idx % 768;
    int m = idx / 768;
    int b = m / 196, n = m % 196;
    int c = k >> 8, rem = k & 255, i = rem >> 4, j = rem & 15;
    int py = n / 14, px = n % 14;
    Acol[idx] = __float2bfloat16(x[((b * 3 + c) * 224 + py * 16 + i) * 224 + px * 16 + j]);
}

// ---------------------------------------------------------------- bf16 MFMA GEMM, 128x128 tile, double-buffered, swizzled
template<int RES, int GELU, int BF16OUT>
__global__ __launch_bounds__(256) void k_mfma_gemm(
    const u16* __restrict__ A, const u16* __restrict__ Bt,
    const float* __restrict__ bias, const float* __restrict__ res,
    float* __restrict__ Cf, __hip_bfloat16* __restrict__ Cb,
    int M, int N, int K)
{
    __shared__ u16 As[2][128 * 64];
    __shared__ u16 Bs[2][128 * 64];
    const int tid = threadIdx.x;
    const int wid = tid >> 6, lane = tid & 63;
    const int m0 = blockIdx.y * 128, n0 = blockIdx.x * 128;
    const int srow = tid >> 3;          // 0..31
    const int selem = (tid & 7) << 3;   // 0..56
    const int wm = (wid >> 1) * 64, wn = (wid & 1) * 64;

    f32x4 acc[4][4] = {};

    auto stage = [&](int buf, int kb) {
        #pragma unroll
        for (int g = 0; g < 4; ++g) {
            int r = g * 32 + srow;
            int sw = selem ^ ((r & 7) << 3);   // pre-swizzled global source, linear LDS dest
            int gr = m0 + r; if (gr > M - 1) gr = M - 1;
            async_copy16(&As[buf][r * 64 + selem], A + (size_t)gr * K + kb + sw);
            async_copy16(&Bs[buf][r * 64 + selem], Bt + (size_t)(n0 + r) * K + kb + sw);
        }
    };

    const int nk = K >> 6;
    stage(0, 0);
    __syncthreads();
    for (int t = 0; t < nk; ++t) {
        const int cur = t & 1;
        if (t + 1 < nk) stage(cur ^ 1, (t + 1) << 6);
        #pragma unroll
        for (int ks = 0; ks < 64; ks += 32) {
            const int kk = ks + ((lane >> 4) << 3);
            bf16x8 af[4], bfr[4];
            #pragma unroll
            for (int i = 0; i < 4; ++i) {
                int r = wm + i * 16 + (lane & 15);
                af[i] = *(const bf16x8*)&As[cur][r * 64 + (kk ^ ((r & 7) << 3))];
            }
            #pragma unroll
            for (int j = 0; j < 4; ++j) {
                int r = wn + j * 16 + (lane & 15);
                bfr[j] = *(const bf16x8*)&Bs[cur][r * 64 + (kk ^ ((r & 7) << 3))];
            }
            #pragma unroll
            for (int i = 0; i < 4; ++i)
                #pragma unroll
                for (int j = 0; j < 4; ++j)
                    acc[i][j] = __builtin_amdgcn_mfma_f32_16x16x32_bf16(af[i], bfr[j], acc[i][j], 0, 0, 0);
        }
        __syncthreads();
    }
    const int cl = lane & 15, rg = (lane >> 4) << 2;
    #pragma unroll
    for (int i = 0; i < 4; ++i) {
        #pragma unroll
        for (int j = 0; j < 4; ++j) {
            const int col = n0 + wn + j * 16 + cl;
            const float bv = bias[col];
            #pragma unroll
            for (int r = 0; r < 4; ++r) {
                const int row = m0 + wm + i * 16 + rg + r;
                if (row >= M) continue;
                float v = acc[i][j][r] + bv;
                if (RES) v += res[(size_t)row * N + col];
                if (GELU) v = 0.5f * v * (1.0f + erff(v * 0.70710678118f));
                if (BF16OUT) Cb[(size_t)row * N + col] = __float2bfloat16(v);
                else         Cf[(size_t)row * N + col] = v;
            }
        }
    }
}

// ---------------------------------------------------------------- bf16 MFMA GEMM, 128x64 tile, double-buffered, swizzled
template<int RES, int GELU, int BF16OUT>
__global__ __launch_bounds__(256) void k_mfma_gemm64(
    const u16* __restrict__ A, const u16* __restrict__ Bt,
    const float* __restrict__ bias, const float* __restrict__ res,
    float* __restrict__ Cf, __hip_bfloat16* __restrict__ Cb,
    int M, int N, int K)
{
    __shared__ u16 As[2][128 * 64];
    __shared__ u16 Bs[2][64 * 64];
    const int tid = threadIdx.x;
    const int wid = tid >> 6, lane = tid & 63;
    const int m0 = blockIdx.y * 128, n0 = blockIdx.x * 64;
    const int srow = tid >> 3;
    const int selem = (tid & 7) << 3;
    const int wm = wid * 32;

    f32x4 acc[2][4] = {};

    auto stage = [&](int buf, int kb) {
        #pragma unroll
        for (int g = 0; g < 4; ++g) {
            int r = g * 32 + srow;
            int sw = selem ^ ((r & 7) << 3);
            int gr = m0 + r; if (gr > M - 1) gr = M - 1;
            async_copy16(&As[buf][r * 64 + selem], A + (size_t)gr * K + kb + sw);
        }
        #pragma unroll
        for (int g = 0; g < 2; ++g) {
            int r = g * 32 + srow;
            int sw = selem ^ ((r & 7) << 3);
            async_copy16(&Bs[buf][r * 64 + selem], Bt + (size_t)(n0 + r) * K + kb + sw);
        }
    };

    const int nk = K >> 6;
    stage(0, 0);
    __syncthreads();
    for (int t = 0; t < nk; ++t) {
        const int cur = t & 1;
        if (t + 1 < nk) stage(cur ^ 1, (t + 1) << 6);
        #pragma unroll
        for (int ks = 0; ks < 64; ks += 32) {
            const int kk = ks + ((lane >> 4) << 3);
            bf16x8 af[2], bfr[4];
            #pragma unroll
            for (int i = 0; i < 2; ++i) {
                int r = wm + i * 16 + (lane & 15);
                af[i] = *(const bf16x8*)&As[cur][r * 64 + (kk ^ ((r & 7) << 3))];
            }
            #pragma unroll
            for (int j = 0; j < 4; ++j) {
                int r = j * 16 + (lane & 15);
                bfr[j] = *(const bf16x8*)&Bs[cur][r * 64 + (kk ^ ((r & 7) << 3))];
            }
            #pragma unroll
            for (int i = 0; i < 2; ++i)
                #pragma unroll
                for (int j = 0; j < 4; ++j)
                    acc[i][j] = __builtin_amdgcn_mfma_f32_16x16x32_bf16(af[i], bfr[j], acc[i][j], 0, 0, 0);
        }
        __syncthreads();
    }
    const int cl = lane & 15, rg = (lane >> 4) << 2;
    #pragma unroll
    for (int i = 0; i < 2; ++i) {
        #pragma unroll
        for (int j = 0; j < 4; ++j) {
            const int col = n0 + j * 16 + cl;
            const float bv = bias[col];
            #pragma unroll
            for (int r = 0; r < 4; ++r) {
                const int row = m0 + wm + i * 16 + rg + r;
                if (row >= M) continue;
                float v = acc[i][j][r] + bv;
                if (RES) v += res[(size_t)row * N + col];
                if (GELU) v = 0.5f * v * (1.0f + erff(v * 0.70710678118f));
                if (BF16OUT) Cb[(size_t)row * N + col] = __float2bfloat16(v);
                else         Cf[(size_t)row * N + col] = v;
            }
        }
    }
}

// ---------------------------------------------------------------- assemble tokens: cls + patches + pos (fp32)
__global__ void k_assemble(const float* __restrict__ ptmp, const float* __restrict__ cls_tok,
                           const float* __restrict__ pos, float* __restrict__ tok) {
    int idx = blockIdx.x * 256 + threadIdx.x;   // < 16*197*384
    int d = idx % 384;
    int t = (idx / 384) % 197;
    int b = idx / (384 * 197);
    float v = (t == 0) ? cls_tok[d] : ptmp[((size_t)b * 196 + t - 1) * 384 + d];
    tok[idx] = v + pos[t * 384 + d];
}

// ---------------------------------------------------------------- layernorm (fp32 compute), OT output
template<typename OT>
__global__ __launch_bounds__(256) void k_ln(const float* __restrict__ X, const float* __restrict__ s,
                                            const float* __restrict__ bb, OT* __restrict__ Y, int rows) {
    int wid = threadIdx.x >> 6, lane = threadIdx.x & 63;
    int row = blockIdx.x * 4 + wid;
    if (row >= rows) return;
    const float* x = X + (size_t)row * 384;
    float v[6], sum = 0.f, sq = 0.f;
    #pragma unroll
    for (int i = 0; i < 6; ++i) { float t = x[lane + 64 * i]; v[i] = t; sum += t; sq += t * t; }
    #pragma unroll
    for (int m = 32; m > 0; m >>= 1) { sum += __shfl_xor(sum, m); sq += __shfl_xor(sq, m); }
    float mean = sum * (1.f / 384.f);
    float var  = sq * (1.f / 384.f) - mean * mean;
    float rstd = rsqrtf(var + 1e-6f);
    OT* y = Y + (size_t)row * 384;
    #pragma unroll
    for (int i = 0; i < 6; ++i) {
        int d = lane + 64 * i;
        float o = (v[i] - mean) * rstd * s[d] + bb[d];
        y[d] = (OT)o;
    }
}

// ---------------------------------------------------------------- MFMA attention
__global__ __launch_bounds__(256) void k_attn_mfma(const u16* __restrict__ qkv, u16* __restrict__ o) {
    __shared__ u16 Ks[208 * 64];       // K rows, XOR-swizzled 16B chunks
    __shared__ u16 VT[64 * 256];       // V^T rows (d, k), swizzled, tail-zeroed
    __shared__ u16 Pl[4][16 * 256];    // per-wave P tile (q_local, k), swizzled
    const int bh = blockIdx.x;
    const int b = bh / 6, hh = bh % 6;
    const u16* base = qkv + (size_t)b * 197 * 1152 + hh * 64;
    const int tid = threadIdx.x, wid = tid >> 6, lane = tid & 63;

    for (int i = tid; i < 64 * 59; i += 256) {
        int d = i / 59, k = 197 + i % 59;
        VT[d * 256 + (k ^ ((d & 7) << 3))] = 0;
    }
    for (int i = tid; i < 64 * 48; i += 256) {
        int q = i / 48, k = 208 + i % 48;
        Pl[q >> 4][(q & 15) * 256 + (k ^ ((q & 7) << 3))] = 0;
    }
    for (int i = tid; i < 197 * 8; i += 256) {
        int r = i >> 3, cc = (i & 7) << 3;
        uint4 v = *(const uint4*)(base + (size_t)r * 1152 + 384 + cc);
        *(uint4*)&Ks[r * 64 + (cc ^ ((r & 7) << 3))] = v;
    }
    for (int i = tid; i < 197 * 8; i += 256) {
        int r = i >> 3, d0 = (i & 7) << 3;
        uint4 v = *(const uint4*)(base + (size_t)r * 1152 + 768 + d0);
        const u16* pv = (const u16*)&v;
        #pragma unroll
        for (int j = 0; j < 8; ++j) {
            int d = d0 + j;
            VT[d * 256 + (r ^ ((d & 7) << 3))] = pv[j];
        }
    }
    __syncthreads();

    const int g = lane >> 4, c = lane & 15;
    const int t0 = blockIdx.y * 7;
    const int nt = blockIdx.y ? 6 : 7;
    for (int t = wid; t < nt; t += 4) {
        const int qt = t0 + t;
        const int q0 = qt * 16;
        int qrow = q0 + c; if (qrow > 196) qrow = 196;
        bf16x8 aq[2];
        aq[0] = *(const bf16x8*)(base + (size_t)qrow * 1152 + g * 8);
        aq[1] = *(const bf16x8*)(base + (size_t)qrow * 1152 + 32 + g * 8);

        f32x4 acc[13] = {};
        #pragma unroll
        for (int j = 0; j < 13; ++j) {
            int kr = j * 16 + c;
            bf16x8 b0 = *(const bf16x8*)&Ks[kr * 64 + ((g * 8) ^ ((kr & 7) << 3))];
            bf16x8 b1 = *(const bf16x8*)&Ks[kr * 64 + ((32 + g * 8) ^ ((kr & 7) << 3))];
            acc[j] = __builtin_amdgcn_mfma_f32_16x16x32_bf16(aq[0], b0, acc[j], 0, 0, 0);
            acc[j] = __builtin_amdgcn_mfma_f32_16x16x32_bf16(aq[1], b1, acc[j], 0, 0, 0);
        }

        float sc[13][4];
        float mr[4] = {-1e30f, -1e30f, -1e30f, -1e30f};
        #pragma unroll
        for (int j = 0; j < 13; ++j) {
            bool valid = (j * 16 + c) < 197;
            #pragma unroll
            for (int r = 0; r < 4; ++r) {
                float v = valid ? acc[j][r] * 0.125f : -1e30f;
                sc[j][r] = v;
                mr[r] = fmaxf(mr[r], v);
            }
        }
        #pragma unroll
        for (int r = 0; r < 4; ++r) {
            #pragma unroll
            for (int msk = 1; msk <= 8; msk <<= 1) mr[r] = fmaxf(mr[r], __shfl_xor(mr[r], msk));
        }
        float lr[4] = {0.f, 0.f, 0.f, 0.f};
        #pragma unroll
        for (int j = 0; j < 13; ++j)
            #pragma unroll
            for (int r = 0; r < 4; ++r) { float e = __expf(sc[j][r] - mr[r]); sc[j][r] = e; lr[r] += e; }
        #pragma unroll
        for (int r = 0; r < 4; ++r) {
            #pragma unroll
            for (int msk = 1; msk <= 8; msk <<= 1) lr[r] += __shfl_xor(lr[r], msk);
            lr[r] = 1.f / lr[r];
        }
        #pragma unroll
        for (int j = 0; j < 13; ++j) {
            int col = j * 16 + c;
            #pragma unroll
            for (int r = 0; r < 4; ++r) {
                int q = g * 4 + r;
                Pl[wid][q * 256 + (col ^ ((q & 7) << 3))] = f2b(sc[j][r] * lr[r]);
            }
        }
        asm volatile("s_waitcnt lgkmcnt(0)" ::: "memory");

        f32x4 av[4] = {};
        #pragma unroll
        for (int ks = 0; ks < 7; ++ks) {
            int kk = ks * 32 + g * 8;
            bf16x8 ap = *(const bf16x8*)&Pl[wid][c * 256 + (kk ^ ((c & 7) << 3))];
            #pragma unroll
            for (int jd = 0; jd < 4; ++jd) {
                int dr = jd * 16 + c;
                bf16x8 bv = *(const bf16x8*)&VT[dr * 256 + (kk ^ ((dr & 7) << 3))];
                av[jd] = __builtin_amdgcn_mfma_f32_16x16x32_bf16(ap, bv, av[jd], 0, 0, 0);
            }
        }
        #pragma unroll
        for (int jd = 0; jd < 4; ++jd) {
            #pragma unroll
            for (int r = 0; r < 4; ++r) {
                int q = q0 + g * 4 + r;
                if (q < 197)
                    o[((size_t)b * 197 + q) * 384 + hh * 64 + jd * 16 + c] = f2b(av[jd][r]);
            }
        }
    }
}

// ---------------------------------------------------------------- feature normalize -> bf16 + cls copy-out
__global__ __launch_bounds__(256) void k_fn(const float* __restrict__ tokn, __hip_bfloat16* __restrict__ fn,
                                            float* __restrict__ out) {
    int wid = threadIdx.x >> 6, lane = threadIdx.x & 63;
    int row = blockIdx.x * 4 + wid;   // < 3136
    int b = row / 196, n = row % 196;
    const float* xr = tokn + ((size_t)b * 197 + 1 + n) * 384;
    const float* cr = tokn + (size_t)b * 197 * 384;
    float v[6], ss = 0.f;
    #pragma unroll
    for (int i = 0; i < 6; ++i) {
        int d = lane + 64 * i;
        float t = xr[d] - cr[d];
        v[i] = t; ss += t * t;
    }
    #pragma unroll
    for (int m = 32; m > 0; m >>= 1) ss += __shfl_xor(ss, m);
    float inv = 1.f / fmaxf(sqrtf(ss), 1e-12f);
    #pragma unroll
    for (int i = 0; i < 6; ++i) fn[(size_t)row * 384 + lane + 64 * i] = __float2bfloat16(v[i] * inv);
    int idx = blockIdx.x * 256 + threadIdx.x;
    if (idx < 6144) out[idx] = tokn[(size_t)(idx / 384) * 197 * 384 + idx % 384];
}

// ---------------------------------------------------------------- proto normalize + transpose -> bf16 (8000, 384)
__global__ __launch_bounds__(256) void k_pn(const float* __restrict__ proto, __hip_bfloat16* __restrict__ pn) {
    int p = blockIdx.x;
    int k = threadIdx.x >> 6, lane = threadIdx.x & 63;
    float v[6], ss = 0.f;
    #pragma unroll
    for (int i = 0; i < 6; ++i) {
        int d = lane + 64 * i;
        float t = proto[((size_t)p * 384 + d) * 4 + k];
        v[i] = t; ss += t * t;
    }
    #pragma unroll
    for (int m = 32; m > 0; m >>= 1) ss += __shfl_xor(ss, m);
    float inv = 1.f / fmaxf(sqrtf(ss), 1e-12f);
    #pragma unroll
    for (int i = 0; i < 6; ++i) pn[((size_t)p * 4 + k) * 384 + lane + 64 * i] = __float2bfloat16(v[i] * inv);
}

// ---------------------------------------------------------------- top4 helper
__device__ __forceinline__ void top4_insert(float v, float& t0, float& t1, float& t2, float& t3) {
    if (v > t3) {
        t3 = v;
        if (t3 > t2) { float t = t2; t2 = t3; t3 = t; }
        if (t2 > t1) { float t = t1; t1 = t2; t2 = t; }
        if (t1 > t0) { float t = t0; t0 = t1; t1 = t; }
    }
}

// ---------------------------------------------------------------- dist: bf16 MFMA GEMM + fused top-4 + score
// (round-4 version: BK=64 single-buffer, global_load_lds with pre-swizzled source, 0 conflicts)
__global__ __launch_bounds__(256) void k_dist_mfma(
    const __hip_bfloat16* __restrict__ fnb, const __hip_bfloat16* __restrict__ pnb,
    const float* __restrict__ psel, float* __restrict__ out)
{
    __shared__ u16 Ap[128 * 64];
    __shared__ u16 Bf[208 * 64];
    const u16* fn = (const u16*)fnb;
    const u16* pn = (const u16*)pnb;
    const int b = blockIdx.x;
    const int pb = blockIdx.y;
    const int tid = threadIdx.x, wid = tid >> 6, lane = tid & 63;
    const int srow = tid >> 3;
    const int selem = (tid & 7) << 3;

    f32x4 acc[2][13] = {};

    for (int kt = 0; kt < 384; kt += 64) {
        __syncthreads();
        #pragma unroll
        for (int g = 0; g < 4; ++g) {
            int r = g * 32 + srow;
            int gr = pb * 128 + r; if (gr > 7999) gr = 7999;
            async_copy16(&Ap[r * 64 + selem],
                         pn + (size_t)gr * 384 + kt + (selem ^ ((r & 7) << 3)));
        }
        #pragma unroll
        for (int g = 0; g < 7; ++g) {
            int r = g * 32 + srow;
            if (r < 208) {
                int fr = r > 195 ? 195 : r;
                async_copy16(&Bf[r * 64 + selem],
                             fn + ((size_t)b * 196 + fr) * 384 + kt + (selem ^ ((r & 7) << 3)));
            }
        }
        __syncthreads();
        #pragma unroll
        for (int ks = 0; ks < 64; ks += 32) {
            const int kk = ks + ((lane >> 4) << 3);
            bf16x8 af[2];
            #pragma unroll
            for (int i = 0; i < 2; ++i) {
                int r = wid * 32 + i * 16 + (lane & 15);
                af[i] = *(const bf16x8*)&Ap[r * 64 + (kk ^ ((r & 7) << 3))];
            }
            #pragma unroll
            for (int j = 0; j < 13; ++j) {
                int r = j * 16 + (lane & 15);
                bf16x8 bj = *(const bf16x8*)&Bf[r * 64 + (kk ^ ((r & 7) << 3))];
                acc[0][j] = __builtin_amdgcn_mfma_f32_16x16x32_bf16(af[0], bj, acc[0][j], 0, 0, 0);
                acc[1][j] = __builtin_amdgcn_mfma_f32_16x16x32_bf16(af[1], bj, acc[1][j], 0, 0, 0);
            }
        }
    }
    const int cl = lane & 15;
    #pragma unroll
    for (int mi = 0; mi < 2; ++mi) {
        float t0 = -1e30f, t1 = -1e30f, t2 = -1e30f, t3 = -1e30f;
        #pragma unroll
        for (int j = 0; j < 13; ++j) {
            if (j * 16 + cl >= 196) continue;
            #pragma unroll
            for (int r = 0; r < 4; ++r) top4_insert(acc[mi][j][r], t0, t1, t2, t3);
        }
        #pragma unroll
        for (int m = 1; m <= 8; m <<= 1) {
            float u0 = __shfl_xor(t0, m), u1 = __shfl_xor(t1, m);
            float u2 = __shfl_xor(t2, m), u3 = __shfl_xor(t3, m);
            top4_insert(u0, t0, t1, t2, t3);
            top4_insert(u1, t0, t1, t2, t3);
            top4_insert(u2, t0, t1, t2, t3);
            top4_insert(u3, t0, t1, t2, t3);
        }
        if (cl == 0) {
            int proto = pb * 32 + wid * 8 + mi * 4 + (lane >> 4);
            if (proto < 2000) {
                float sl[4], fac = 1e-10f;
                #pragma unroll
                for (int i = 0; i < 4; ++i) {
                    sl[i] = 1.f / (1.f + expf(-psel[proto * 4 + i] * 100.f));
                    fac += sl[i];
                }
                float score = (t0 * sl[0] + t1 * sl[1] + t2 * sl[2] + t3 * sl[3]) * 4.f / fac;
                out[6144 + (size_t)b * 2000 + proto] = score;
            }
        }
    }
}

// ---------------------------------------------------------------- host launcher
extern "C" void kernel_launch(void* const* d_in, const int* in_sizes, int n_in,
                              void* d_out, int out_size, void* d_ws, size_t ws_size,
                              hipStream_t stream) {
    const float* x       = (const float*)d_in[0];
    const float* patch_w = (const float*)d_in[1];
    const float* patch_b = (const float*)d_in[2];
    const float* cls_tok = (const float*)d_in[3];
    const float* pos     = (const float*)d_in[4];
    const float* ln1_s   = (const float*)d_in[5];
    const float* ln1_b   = (const float*)d_in[6];
    const float* qkv_w   = (const float*)d_in[7];
    const float* qkv_b   = (const float*)d_in[8];
    const float* proj_w  = (const float*)d_in[9];
    const float* proj_b  = (const float*)d_in[10];
    const float* ln2_s   = (const float*)d_in[11];
    const float* ln2_b   = (const float*)d_in[12];
    const float* fc1_w   = (const float*)d_in[13];
    const float* fc1_b   = (const float*)d_in[14];
    const float* fc2_w   = (const float*)d_in[15];
    const float* fc2_b   = (const float*)d_in[16];
    const float* norm_s  = (const float*)d_in[17];
    const float* norm_b  = (const float*)d_in[18];
    const float* proto   = (const float*)d_in[19];
    const float* psel    = (const float*)d_in[20];
    float* out = (float*)d_out;
    char* w = (char*)d_ws;

    __hip_bfloat16* wPb  = (__hip_bfloat16*)(w);             // 589824
    __hip_bfloat16* wQ   = (__hip_bfloat16*)(w + 589824);    // 5308416
    __hip_bfloat16* wPr  = (__hip_bfloat16*)(w + 5898240);   // 1769472
    __hip_bfloat16* wF1  = (__hip_bfloat16*)(w + 7667712);   // 7077888
    __hip_bfloat16* wF2  = (__hip_bfloat16*)(w + 14745600);  // 7077888
    __hip_bfloat16* Acol = (__hip_bfloat16*)(w + 21823488);  // 4816896
    float*          ptmp = (float*)         (w + 26640384);  // 4816896
    float*          tok  = (float*)         (w + 31457280);  // 4841472
    __hip_bfloat16* hbf  = (__hip_bfloat16*)(w + 36298752);  // 2420736
    __hip_bfloat16* qkvb = (__hip_bfloat16*)(w + 38719488);  // 7262208
    __hip_bfloat16* aob  = (__hip_bfloat16*)(w + 53243904);  // 2420736
    __hip_bfloat16* hbig = (__hip_bfloat16*)(w + 55664640);  // 9682944
    float*          hf   = (float*)         (w + 65347584);  // 4841472
    __hip_bfloat16* fnb  = (__hip_bfloat16*)(w + 70189056);  // 2408448
    __hip_bfloat16* pnb  = (__hip_bfloat16*)(w + 72597504);  // 6144000

    k_cvt<<<1152, 256, 0, stream>>>(patch_w, wPb, 294912);
    k_wt<<<dim3(36, 12, 6), 256, 0, stream>>>(qkv_w, wQ, 384, 1152);
    k_wt<<<dim3(12, 12, 6), 256, 0, stream>>>(proj_w, wPr, 384, 384);
    k_wt<<<dim3(48, 12, 6), 256, 0, stream>>>(fc1_w, wF1, 384, 1536);
    k_wt<<<dim3(12, 48, 6), 256, 0, stream>>>(fc2_w, wF2, 1536, 384);

    k_im2col<<<9408, 256, 0, stream>>>(x, Acol);
    k_mfma_gemm64<0,0,0><<<dim3(6, 25), 256, 0, stream>>>(
        (const u16*)Acol, (const u16*)wPb, patch_b, nullptr, ptmp, nullptr, 3136, 384, 768);
    k_assemble<<<4728, 256, 0, stream>>>(ptmp, cls_tok, pos, tok);

    for (int l = 0; l < 6; ++l) {
        k_ln<__hip_bfloat16><<<788, 256, 0, stream>>>(tok, ln1_s + l * 384, ln1_b + l * 384, hbf, MROWS);
        k_mfma_gemm<0,0,1><<<dim3(9, 25), 256, 0, stream>>>(
            (const u16*)hbf, (const u16*)(wQ + (size_t)l * 1152 * 384), qkv_b + l * 1152,
            nullptr, nullptr, qkvb, MROWS, 1152, 384);
        k_attn_mfma<<<dim3(96, 2), 256, 0, stream>>>((const u16*)qkvb, (u16*)aob);
        k_mfma_gemm64<1,0,0><<<dim3(6, 25), 256, 0, stream>>>(
            (const u16*)aob, (const u16*)(wPr + (size_t)l * 384 * 384), proj_b + l * 384,
            tok, tok, nullptr, MROWS, 384, 384);
        k_ln<__hip_bfloat16><<<788, 256, 0, stream>>>(tok, ln2_s + l * 384, ln2_b + l * 384, hbf, MROWS);
        k_mfma_gemm<0,1,1><<<dim3(12, 25), 256, 0, stream>>>(
            (const u16*)hbf, (const u16*)(wF1 + (size_t)l * 1536 * 384), fc1_b + l * 1536,
            nullptr, nullptr, hbig, MROWS, 1536, 384);
        k_mfma_gemm64<1,0,0><<<dim3(6, 25), 256, 0, stream>>>(
            (const u16*)hbig, (const u16*)(wF2 + (size_t)l * 384 * 1536), fc2_b + l * 384,
            tok, tok, nullptr, MROWS, 384, 1536);
    }

    k_ln<float><<<788, 256, 0, stream>>>(tok, norm_s, norm_b, hf, MROWS);
    k_fn<<<784, 256, 0, stream>>>(hf, fnb, out);
    k_pn<<<2000, 256, 0, stream>>>(proto, pnb);
    k_dist_mfma<<<dim3(16, 63), 256, 0, stream>>>(fnb, pnb, psel, out);
}